// Round 8
// baseline (932970.117 us; speedup 1.0000x reference)
//
#include <hip/hip_runtime.h>
#include <math.h>

#define NPTS 87296
#define NCLS 16
#define KPOS 256
#define KHN  2048
#define TILES 341           // NPTS / 256 exactly (one 256-point tile each)
#define MAXG  512           // max cooperative grid we attempt
#define CAP  4096           // compacted-candidate capacity (slow path beyond)
#define PI_F   3.14159265358979323846f
#define HPI_F  1.57079632679489661923f

struct InPtrs { const float* p[40]; };
// input index = pre*20 + lvl*4 + {cls:0, box:1, ang:2, ctr:3}; pre: t=0, s=1

// ---------------- persistent device scratch (rewritten every call) ----------------
__device__ float g_max_vals[NPTS];
__device__ float g_sig_tiou[NPTS];
__device__ float g_sig_cls_max[NPTS];
__device__ int   g_class_ind[NPTS];
__device__ int   g_pos_mask[NPTS];
__device__ int   g_hn_mask[NPTS];
__device__ int   g_hnflag[NPTS];          // 1 = loc target overridden by aggregated hn
__device__ float g_loc_targets[NPTS * 5]; // only hn slots are written/read
__device__ float g_bsum[TILES];
__device__ float g_bsumsq[TILES];
__device__ int   g_bcnt[TILES];
__device__ int   g_bpos[TILES];
__device__ int   g_bhn[TILES];
__device__ int   g_total_pos;
__device__ int   g_total_hn;
__device__ int   g_fallback;
__device__ int   g_pos_cand[CAP];
__device__ int   g_hn_cand[CAP];
__device__ int   g_pidx[KPOS];
__device__ int   g_pvalid[KPOS];
__device__ float g_pv[KPOS];
__device__ int   g_hidx[KHN];
__device__ int   g_hvalid[KHN];
__device__ float g_pos_bbox[KPOS * 5];
__device__ float g_pos_cor[KPOS * 8];
__device__ float g_pos_area[KPOS];
__device__ float g_pos_scale[KPOS];
__device__ int   g_pos_class[KPOS];
__device__ float g_hn_px[KHN];
__device__ float g_hn_py[KHN];
__device__ float g_hn_cor[KHN * 8];
__device__ float g_hn_area[KHN];
__device__ float g_hn_scale[KHN];
__device__ int   g_hn_class[KHN];
__device__ float g_partials[TILES * 6];

// ---------------- fast grid barrier: per-block flag lines (parallel observation) ----------------
// R7 measured ~24 us/barrier with all waiters RMW-spinning one address (same-address
// RMWs serialize at the coherent point). Fix: one padded flag per block; the last
// arriver's 256 threads release all flags in parallel (distinct addresses), and each
// waiter polls only its own flag. Monotonic epoch targets survive graph replays.
__device__ unsigned long long g_bar_cnt = 0ull;
__device__ int g_bar_flag[MAXG * 32];     // 128 B stride per block

__device__ __forceinline__ void gridbar() {
  __shared__ int s_tgt, s_last;
  __syncthreads();
  if (threadIdx.x == 0) {
    __threadfence();  // publish this block's plain global writes
    unsigned long long i = atomicAdd(&g_bar_cnt, 1ull);
    unsigned long long nb = (unsigned long long)gridDim.x;
    s_tgt = (int)(i / nb) + 1;
    s_last = ((i % nb) == nb - 1ull) ? 1 : 0;
  }
  __syncthreads();
  int target = s_tgt;
  if (s_last) {
    for (int f = threadIdx.x; f < (int)gridDim.x; f += blockDim.x)
      atomicExch(&g_bar_flag[f * 32], target);    // parallel release (distinct lines)
  } else if (threadIdx.x == 0) {
    int guard = 0;
    while (atomicAdd(&g_bar_flag[blockIdx.x * 32], 0) < target) {  // own line only
      __builtin_amdgcn_s_sleep(1);
      if (++guard > (1 << 20)) break;   // insurance: fail loud, not hang
    }
  }
  __syncthreads();
  if (threadIdx.x == 0) __threadfence();  // invalidate local caches before consuming
  __syncthreads();
}

// ---------------- helpers ----------------
__device__ __forceinline__ float sigmoidf(float x) {
  if (x >= 0.f) return 1.f / (1.f + expf(-x));
  float e = expf(x);
  return e / (1.f + e);
}
__device__ __forceinline__ float crs(float ax, float ay, float bx, float by) {
  return ax * by - ay * bx;
}
__device__ __forceinline__ float mod_pos(float x, float y) {
  float r = fmodf(x, y);
  if (r < 0.f) r += y;
  return r;
}
// monotonic pseudo-angle: strictly increasing map of atan2(dy,dx) -> (-2,2]
__device__ __forceinline__ float pseudo_ang(float dx, float dy) {
  float den = fabsf(dx) + fabsf(dy);
  if (den == 0.f) return 0.f;         // matches atan2(0,0)=0 tie class
  return copysignf(1.f - dx / den, dy);
}
__device__ __forceinline__ void point_info(int n, int& lvl, int& idx, int& hw,
                                           float& px, float& py) {
  int off, wsh; float stride;
  if (n < 65536)      { lvl = 0; off = 0;     wsh = 8; stride = 8.f;   hw = 65536; }
  else if (n < 81920) { lvl = 1; off = 65536; wsh = 7; stride = 16.f;  hw = 16384; }
  else if (n < 86016) { lvl = 2; off = 81920; wsh = 6; stride = 32.f;  hw = 4096; }
  else if (n < 87040) { lvl = 3; off = 86016; wsh = 5; stride = 64.f;  hw = 1024; }
  else                { lvl = 4; off = 87040; wsh = 4; stride = 128.f; hw = 256; }
  idx = n - off;
  int y = idx >> wsh, x = idx & ((1 << wsh) - 1);
  px = ((float)x + 0.5f) * stride;
  py = ((float)y + 0.5f) * stride;
}

// ---------------- radix select paths (rare; 256-thread variants) ----------------
#define MASK_ALL 0
#define MASK_POS 1
#define MASK_HN  2
__device__ __forceinline__ int sel_mask(int mode, int n) {
  return mode == MASK_ALL ? 1 : (mode == MASK_POS ? g_pos_mask[n] : g_hn_mask[n]);
}

__device__ void radix_select_mask(int mode, int K, int* out_idx, int* out_valid, float* out_val,
                                  int* hist, int* scan_a, int* scan_b, int* sh) {
  int tid = threadIdx.x;
  int c = 0;
  for (int n = tid; n < NPTS; n += 256) if (sel_mask(mode, n)) c++;
  scan_a[tid] = c; __syncthreads();
  for (int st = 128; st > 0; st >>= 1) {
    if (tid < st) scan_a[tid] += scan_a[tid + st];
    __syncthreads();
  }
  int total = scan_a[0];
  __syncthreads();

  unsigned kth = 0u;
  if (total > K) {
    unsigned prefix = 0; int rem = K;
    for (int pass = 0; pass < 4; pass++) {
      int shift = 24 - 8 * pass;
      hist[tid] = 0;
      __syncthreads();
      for (int n = tid; n < NPTS; n += 256) {
        if (sel_mask(mode, n)) {
          unsigned k = __float_as_uint(g_max_vals[n]);
          if (pass == 0 || ((k >> (shift + 8)) == prefix))
            atomicAdd(&hist[(k >> shift) & 255], 1);
        }
      }
      __syncthreads();
      if (tid == 0) {
        int cum = 0, b = 255;
        for (; b > 0; b--) {
          if (cum + hist[b] >= rem) break;
          cum += hist[b];
        }
        sh[0] = (int)((prefix << 8) | (unsigned)b);
        sh[1] = rem - cum;
      }
      __syncthreads();
      prefix = (unsigned)sh[0]; rem = sh[1];
      __syncthreads();
    }
    kth = prefix;
  }

  const int chunk = (NPTS + 255) / 256;
  int start = tid * chunk; if (start > NPTS) start = NPTS;
  int end = start + chunk; if (end > NPTS) end = NPTS;
  int cgt = 0, ceq = 0;
  for (int n = start; n < end; n++) {
    if (sel_mask(mode, n)) {
      unsigned k = __float_as_uint(g_max_vals[n]);
      if (k > kth) cgt++;
      else if (k == kth) ceq++;
    }
  }
  scan_a[tid] = cgt; scan_b[tid] = ceq; __syncthreads();
  if (tid == 0) {
    int ag = 0, ae = 0;
    for (int i = 0; i < 256; i++) {
      int tg = scan_a[i], te = scan_b[i];
      scan_a[i] = ag; scan_b[i] = ae;
      ag += tg; ae += te;
    }
    sh[0] = ag; sh[1] = ae;
  }
  __syncthreads();
  int cnt_gt = sh[0], cnt_eq = sh[1];
  int og = scan_a[tid], oe = cnt_gt + scan_b[tid];
  for (int n = start; n < end; n++) {
    if (sel_mask(mode, n)) {
      unsigned k = __float_as_uint(g_max_vals[n]);
      if (k > kth) {
        out_idx[og] = n; out_valid[og] = 1;
        if (out_val) out_val[og] = g_max_vals[n];
        og++;
      } else if (k == kth) {
        if (oe < K) {
          out_idx[oe] = n; out_valid[oe] = 1;
          if (out_val) out_val[oe] = g_max_vals[n];
        }
        oe++;
      }
    }
  }
  int kmc = K - cnt_gt;
  int used = cnt_gt + (cnt_eq < kmc ? cnt_eq : kmc);
  __syncthreads();
  for (int i = used + tid; i < K; i += 256) {
    out_idx[i] = 0; out_valid[i] = 0;
    if (out_val) out_val[i] = -1.f;
  }
  __syncthreads();
}

__device__ void radix_select_list(const int* list, int count, int K,
                                  int* out_idx, int* out_valid, float* out_val,
                                  int* hist, int* scan_a, int* scan_b, int* sh) {
  // requires count > K
  int tid = threadIdx.x;
  unsigned prefix = 0; int rem = K;
  for (int pass = 0; pass < 4; pass++) {
    int shift = 24 - 8 * pass;
    hist[tid] = 0;
    __syncthreads();
    for (int i = tid; i < count; i += 256) {
      unsigned k = __float_as_uint(g_max_vals[list[i]]);
      if (pass == 0 || ((k >> (shift + 8)) == prefix))
        atomicAdd(&hist[(k >> shift) & 255], 1);
    }
    __syncthreads();
    if (tid == 0) {
      int cum = 0, b = 255;
      for (; b > 0; b--) {
        if (cum + hist[b] >= rem) break;
        cum += hist[b];
      }
      sh[0] = (int)((prefix << 8) | (unsigned)b);
      sh[1] = rem - cum;
    }
    __syncthreads();
    prefix = (unsigned)sh[0]; rem = sh[1];
    __syncthreads();
  }
  unsigned kth = prefix;
  int chunk = (count + 255) / 256;
  int start = tid * chunk; if (start > count) start = count;
  int end = start + chunk; if (end > count) end = count;
  int cgt = 0, ceq = 0;
  for (int i = start; i < end; i++) {
    unsigned k = __float_as_uint(g_max_vals[list[i]]);
    if (k > kth) cgt++;
    else if (k == kth) ceq++;
  }
  scan_a[tid] = cgt; scan_b[tid] = ceq; __syncthreads();
  if (tid == 0) {
    int ag = 0, ae = 0;
    for (int i = 0; i < 256; i++) {
      int tg = scan_a[i], te = scan_b[i];
      scan_a[i] = ag; scan_b[i] = ae;
      ag += tg; ae += te;
    }
    sh[0] = ag;
  }
  __syncthreads();
  int cnt_gt = sh[0];
  int og = scan_a[tid], oe = cnt_gt + scan_b[tid];
  for (int i = start; i < end; i++) {
    int n = list[i];
    unsigned k = __float_as_uint(g_max_vals[n]);
    if (k > kth) {
      out_idx[og] = n; out_valid[og] = 1;
      if (out_val) out_val[og] = g_max_vals[n];
      og++;
    } else if (k == kth) {
      if (oe < K) {
        out_idx[oe] = n; out_valid[oe] = 1;
        if (out_val) out_val[oe] = g_max_vals[n];
      }
      oe++;
    }
  }
  __syncthreads();
}

// ---------------- decode helper ----------------
__device__ void decode_box(int n, const InPtrs& P, float* bb, float* cor,
                           float& area, float& scale, int& cls_out,
                           float* opx, float* opy) {
  int lvl, idx, hw; float px, py;
  point_info(n, lvl, idx, hw, px, py);
  const float* box = P.p[lvl * 4 + 1];
  const float* ang = P.p[lvl * 4 + 2];
  float l = box[idx], t = box[hw + idx], r = box[2 * hw + idx], b = box[3 * hw + idx];
  float a = ang[idx];
  float ca = cosf(a), sa = sinf(a);
  float w = l + r, h = t + b;
  float oxl = (r - l) * 0.5f, oyl = (b - t) * 0.5f;
  float ox = ca * oxl - sa * oyl;
  float oy = sa * oxl + ca * oyl;
  float an = mod_pos(a + HPI_F, PI_F) - HPI_F;
  float cx = px + ox, cy = py + oy;
  bb[0] = cx; bb[1] = cy; bb[2] = w; bb[3] = h; bb[4] = an;
  float c2 = cosf(an), s2 = sinf(an);
  const float dxs[4] = {-0.5f, 0.5f, 0.5f, -0.5f};
  const float dys[4] = {-0.5f, -0.5f, 0.5f, 0.5f};
#pragma unroll
  for (int k = 0; k < 4; k++) {
    float dx = dxs[k] * w, dy = dys[k] * h;
    cor[2 * k]     = cx + dx * c2 - dy * s2;
    cor[2 * k + 1] = cy + dx * s2 + dy * c2;
  }
  area = fabsf(w * h);
  scale = (float)lvl;
  cls_out = g_class_ind[n];
  if (opx) { *opx = px; *opy = py; }
}

// ---------------- convex quad intersection — fully register-resident ----------------
#define BPASS(KK, JJ)                                                      \
  _Pragma("unroll")                                                        \
  for (int i = 0; i < 32; i++) {                                           \
    int l = i ^ (JJ);                                                      \
    if (l > i) {                                                           \
      bool up = ((i & (KK)) == 0);                                         \
      float aa = sa_[i], ab = sa_[l];                                      \
      bool sw = up ? (aa > ab) : (aa < ab);                                \
      sa_[i] = sw ? ab : aa; sa_[l] = sw ? aa : ab;                        \
      float xi = sx_[i], xl = sx_[l];                                      \
      sx_[i] = sw ? xl : xi; sx_[l] = sw ? xi : xl;                        \
      float yi = sy_[i], yl = sy_[l];                                      \
      sy_[i] = sw ? yl : yi; sy_[l] = sw ? yi : yl;                        \
    }                                                                      \
  }

__device__ float inter_area(const float* __restrict__ A, const float* __restrict__ B) {
  float ax[4], ay[4], bx[4], by[4];
#pragma unroll
  for (int i = 0; i < 4; i++) {
    ax[i] = A[2 * i]; ay[i] = A[2 * i + 1];
    bx[i] = B[2 * i]; by[i] = B[2 * i + 1];
  }
  float dax[4], day[4], dbx[4], dby[4];
#pragma unroll
  for (int i = 0; i < 4; i++) {
    int i1 = (i + 1) & 3;
    dax[i] = ax[i1] - ax[i]; day[i] = ay[i1] - ay[i];
    dbx[i] = bx[i1] - bx[i]; dby[i] = by[i1] - by[i];
  }
  float px[24], py[24]; bool val[24];
#pragma unroll
  for (int i = 0; i < 4; i++) {
#pragma unroll
    for (int j = 0; j < 4; j++) {
      float dx = bx[j] - ax[i], dy = by[j] - ay[i];
      float den = crs(dax[i], day[i], dbx[j], dby[j]);
      float ad = fabsf(den);
      float ds = (ad < 1e-10f) ? 1.0f : den;
      float t = crs(dx, dy, dbx[j], dby[j]) / ds;
      float u = crs(dx, dy, dax[i], day[i]) / ds;
      bool ok = (ad > 1e-10f) & (t >= 0.f) & (t <= 1.f) & (u >= 0.f) & (u <= 1.f);
      int k = i * 4 + j;
      px[k] = ax[i] + t * dax[i];
      py[k] = ay[i] + t * day[i];
      val[k] = ok;
    }
  }
#pragma unroll
  for (int i = 0; i < 4; i++) {   // corners of A inside B
    bool ge = true, le = true;
#pragma unroll
    for (int j = 0; j < 4; j++) {
      float s = crs(dbx[j], dby[j], ax[i] - bx[j], ay[i] - by[j]);
      ge = ge && (s >= -1e-9f);
      le = le && (s <= 1e-9f);
    }
    val[16 + i] = ge || le; px[16 + i] = ax[i]; py[16 + i] = ay[i];
  }
#pragma unroll
  for (int j = 0; j < 4; j++) {   // corners of B inside A
    bool ge = true, le = true;
#pragma unroll
    for (int i = 0; i < 4; i++) {
      float s = crs(dax[i], day[i], bx[j] - ax[i], by[j] - ay[i]);
      ge = ge && (s >= -1e-9f);
      le = le && (s <= 1e-9f);
    }
    val[20 + j] = ge || le; px[20 + j] = bx[j]; py[20 + j] = by[j];
  }
  int n = 0; float sx = 0.f, sy = 0.f;
#pragma unroll
  for (int k = 0; k < 24; k++) if (val[k]) { n++; sx += px[k]; sy += py[k]; }
  float dn = (float)(n > 1 ? n : 1);
  float cx = sx / dn, cy = sy / dn;

  // 24 real slots (invalid collapse to centroid) + 8 +INF dummies; non-stable
  // network OK: angle ties only among identical centroid points (zero terms).
  float sa_[32], sx_[32], sy_[32];
#pragma unroll
  for (int k = 0; k < 24; k++) {
    float X = val[k] ? px[k] : cx;
    float Y = val[k] ? py[k] : cy;
    sx_[k] = X; sy_[k] = Y;
    sa_[k] = pseudo_ang(X - cx, Y - cy);
  }
#pragma unroll
  for (int k = 24; k < 32; k++) {
    sa_[k] = __int_as_float(0x7f800000);  // +inf
    sx_[k] = cx; sy_[k] = cy;
  }
  BPASS(2, 1)
  BPASS(4, 2)  BPASS(4, 1)
  BPASS(8, 4)  BPASS(8, 2)  BPASS(8, 1)
  BPASS(16, 8) BPASS(16, 4) BPASS(16, 2) BPASS(16, 1)
  BPASS(32, 16) BPASS(32, 8) BPASS(32, 4) BPASS(32, 2) BPASS(32, 1)

  float s2 = 0.f;
#pragma unroll
  for (int k = 0; k < 24; k++) {
    int k1 = (k + 1) % 24;
    s2 += crs(sx_[k] - cx, sy_[k] - cy, sx_[k1] - cx, sy_[k1] - cy);
  }
  float area = 0.5f * fabsf(s2);
  return (n >= 3) ? area : 0.f;
}

// ---------------- shared per-phase device logic (used by fused + fallback) ----------------
__device__ void phaseA_tile(int t, const InPtrs& P, float red[3][256]) {
  int tid = threadIdx.x;
  int n = t * 256 + tid;
  int lvl, idx, hw; float px, py;
  point_info(n, lvl, idx, hw, px, py);
  const float* cls = P.p[lvl * 4 + 0];
  const float* ctr = P.p[lvl * 4 + 3];
  float stiou = sigmoidf(ctr[idx]);
  float mv = -1.f, scm = 0.f; int ci = 0;
  for (int c = 0; c < NCLS; c++) {
    float sc = sigmoidf(cls[c * hw + idx]);
    if (sc > scm) scm = sc;
    float j = sc * stiou;
    if (j > mv) { mv = j; ci = c; }
  }
  g_max_vals[n] = mv;
  g_class_ind[n] = ci;
  g_sig_tiou[n] = stiou;
  g_sig_cls_max[n] = scm;
  g_hnflag[n] = 0;
  float isc = (mv >= 0.1f) ? 1.f : 0.f;
  __syncthreads();
  red[0][tid] = isc; red[1][tid] = isc * mv; red[2][tid] = isc * mv * mv;
  __syncthreads();
  for (int st = 128; st > 0; st >>= 1) {
    if (tid < st) {
      red[0][tid] += red[0][tid + st];
      red[1][tid] += red[1][tid + st];
      red[2][tid] += red[2][tid + st];
    }
    __syncthreads();
  }
  if (tid == 0) {
    g_bcnt[t] = (int)red[0][0];
    g_bsum[t] = red[1][0];
    g_bsumsq[t] = red[2][0];
  }
}

__device__ float compute_thresh(float red[2][256], int* si0) {
  int tid = threadIdx.x;
  int c = 0; float s = 0.f, q = 0.f;
  for (int i = tid; i < TILES; i += 256) { c += g_bcnt[i]; s += g_bsum[i]; q += g_bsumsq[i]; }
  __syncthreads();
  si0[tid] = c; red[0][tid] = s; red[1][tid] = q; __syncthreads();
  for (int st = 128; st > 0; st >>= 1) {
    if (tid < st) {
      si0[tid] += si0[tid + st];
      red[0][tid] += red[0][tid + st];
      red[1][tid] += red[1][tid + st];
    }
    __syncthreads();
  }
  int nc = si0[0]; float sum = red[0][0], sumsq = red[1][0];
  float mean = sum / (float)(nc > 1 ? nc : 1);
  float E = sumsq - 2.f * mean * sum + (float)nc * mean * mean;
  if (E < 0.f) E = 0.f;
  float var = E / (float)((nc - 1) > 1 ? (nc - 1) : 1);
  float th = fminf(mean + sqrtf(var), 0.4f);
  if (nc == 0) th = __int_as_float(0x7f800000);  // +inf
  return th;
}

__device__ void phaseB_tile(int t, float th, int* si0, int* si1) {
  int tid = threadIdx.x;
  int n = t * 256 + tid;
  float v = g_max_vals[n];
  int pm = (v >= th) ? 1 : 0;
  int hm = (v >= 0.1f && v < th) ? 1 : 0;
  g_pos_mask[n] = pm; g_hn_mask[n] = hm;
  __syncthreads();
  si0[tid] = pm; si1[tid] = hm; __syncthreads();
  for (int st = 128; st > 0; st >>= 1) {
    if (tid < st) { si0[tid] += si0[tid + st]; si1[tid] += si1[tid + st]; }
    __syncthreads();
  }
  if (tid == 0) { g_bpos[t] = si0[0]; g_bhn[t] = si1[0]; }
}

__device__ void totals_tphn(int* si0, int* si1, int& tp, int& thn) {
  int tid = threadIdx.x;
  int cp = 0, ch = 0;
  for (int i = tid; i < TILES; i += 256) { cp += g_bpos[i]; ch += g_bhn[i]; }
  __syncthreads();
  si0[tid] = cp; si1[tid] = ch; __syncthreads();
  for (int st = 128; st > 0; st >>= 1) {
    if (tid < st) { si0[tid] += si0[tid + st]; si1[tid] += si1[tid + st]; }
    __syncthreads();
  }
  tp = si0[0]; thn = si1[0];
  __syncthreads();
}

__device__ void phaseC_tile(int t, int* si0, int* si1) {
  int tid = threadIdx.x;
  // exclusive offset for tile t
  int cp = 0, ch = 0;
  for (int i = tid; i < t; i += 256) { cp += g_bpos[i]; ch += g_bhn[i]; }
  __syncthreads();
  si0[tid] = cp; si1[tid] = ch; __syncthreads();
  for (int st = 128; st > 0; st >>= 1) {
    if (tid < st) { si0[tid] += si0[tid + st]; si1[tid] += si1[tid + st]; }
    __syncthreads();
  }
  int poff = si0[0], hoff = si1[0];
  __syncthreads();
  // in-tile inclusive scan of masks
  int n = t * 256 + tid;
  int pm = g_pos_mask[n], hm = g_hn_mask[n];
  si0[tid] = pm; si1[tid] = hm; __syncthreads();
  for (int off = 1; off < 256; off <<= 1) {
    int ap = (tid >= off) ? si0[tid - off] : 0;
    int ah = (tid >= off) ? si1[tid - off] : 0;
    __syncthreads();
    si0[tid] += ap; si1[tid] += ah;
    __syncthreads();
  }
  if (pm) { int o = poff + si0[tid] - pm; if (o < CAP) g_pos_cand[o] = n; }
  if (hm) { int o = hoff + si1[tid] - hm; if (o < CAP) g_hn_cand[o] = n; }
  __syncthreads();
}

__device__ void slow_select_block(int tp, int thn, int fallback,
                                  int* hist, int* si0, int* si1, int* sh_i) {
  int tid = threadIdx.x;
  if (!fallback && tp <= KPOS) {
    for (int i = tid; i < KPOS; i += 256) {
      if (i < tp) {
        int m = g_pos_cand[i];
        g_pidx[i] = m; g_pvalid[i] = 1; g_pv[i] = g_max_vals[m];
      } else { g_pidx[i] = 0; g_pvalid[i] = 0; g_pv[i] = -1.f; }
    }
    __syncthreads();
  } else if (!fallback && tp <= CAP) {
    radix_select_list(g_pos_cand, tp, KPOS, g_pidx, g_pvalid, g_pv, hist, si0, si1, sh_i);
  } else if (!fallback) {
    radix_select_mask(MASK_POS, KPOS, g_pidx, g_pvalid, g_pv, hist, si0, si1, sh_i);
  } else {
    radix_select_mask(MASK_ALL, 10, g_pidx, g_pvalid, g_pv, hist, si0, si1, sh_i);
    for (int i = tid; i < 10; i += 256)
      if (g_pvalid[i]) g_pos_mask[g_pidx[i]] = 1;
    for (int i = 10 + tid; i < KPOS; i += 256) {
      g_pidx[i] = 0; g_pvalid[i] = 0; g_pv[i] = -1.f;
    }
    __syncthreads();
  }
  if (thn <= KHN) {
    for (int i = tid; i < KHN; i += 256) {
      if (i < thn) { g_hidx[i] = g_hn_cand[i]; g_hvalid[i] = 1; }
      else { g_hidx[i] = 0; g_hvalid[i] = 0; }
    }
  } else if (thn <= CAP) {
    radix_select_list(g_hn_cand, thn, KHN, g_hidx, g_hvalid, (float*)0, hist, si0, si1, sh_i);
  } else {
    radix_select_mask(MASK_HN, KHN, g_hidx, g_hvalid, (float*)0, hist, si0, si1, sh_i);
  }
}

__device__ void decode_slot(int i, const InPtrs& P, bool slow, int tp, int thn) {
  if (i < KPOS) {
    int pv_valid; int m; float pvv;
    if (slow) { pv_valid = g_pvalid[i]; m = g_pidx[i]; pvv = g_pv[i]; }
    else {
      pv_valid = (i < tp) ? 1 : 0;
      m = pv_valid ? g_pos_cand[i] : 0;
      pvv = pv_valid ? g_max_vals[m] : -1.f;
      g_pvalid[i] = pv_valid; g_pv[i] = pvv;
    }
    float bb[5] = {0,0,0,0,0}, cor[8] = {0,0,0,0,0,0,0,0};
    float ar = 0.f, sc = 0.f; int cl = 0;
    if (pv_valid) decode_box(m, P, bb, cor, ar, sc, cl, (float*)0, (float*)0);
#pragma unroll
    for (int k = 0; k < 5; k++) g_pos_bbox[i * 5 + k] = bb[k];
#pragma unroll
    for (int k = 0; k < 8; k++) g_pos_cor[i * 8 + k] = cor[k];
    g_pos_area[i] = ar; g_pos_scale[i] = sc; g_pos_class[i] = cl;
  } else if (i < KPOS + KHN) {
    int h = i - KPOS;
    int hv; int m;
    if (slow) { hv = g_hvalid[h]; m = g_hidx[h]; }
    else {
      hv = (h < thn) ? 1 : 0;
      m = hv ? g_hn_cand[h] : 0;
      g_hvalid[h] = hv; g_hidx[h] = m;
    }
    float bb[5] = {0,0,0,0,0}, cor[8] = {0,0,0,0,0,0,0,0};
    float ar = 0.f, sc = 0.f, px = 0.f, py = 0.f; int cl = 0;
    if (hv) decode_box(m, P, bb, cor, ar, sc, cl, &px, &py);
#pragma unroll
    for (int k = 0; k < 8; k++) g_hn_cor[h * 8 + k] = cor[k];
    g_hn_area[h] = ar; g_hn_scale[h] = sc; g_hn_class[h] = cl;
    g_hn_px[h] = px; g_hn_py[h] = py;
  }
}

__device__ void iou_hn(int h, float red[7][256]) {
  const int j = threadIdx.x;
  const int hv = g_hvalid[h];
  float wsum = 0.f, wb[5] = {0,0,0,0,0}, anyv = 0.f;
  if (hv && g_pvalid[j]) {
    bool valid = (g_pos_class[j] == g_hn_class[h]) &&
                 (fabsf(g_pos_scale[j] - g_hn_scale[h]) <= 1.0f);
    if (valid) {
      float cx = g_pos_bbox[j * 5 + 0], cy = g_pos_bbox[j * 5 + 1];
      float bw = g_pos_bbox[j * 5 + 2], bh = g_pos_bbox[j * 5 + 3];
      float an = g_pos_bbox[j * 5 + 4];
      float ca = cosf(an), sa = sinf(an);
      float dx = g_hn_px[h] - cx, dy = g_hn_py[h] - cy;
      float ox = ca * dx + sa * dy, oy = -sa * dx + ca * dy;
      float m = fminf(fminf(bw * 0.5f + ox, bw * 0.5f - ox),
                      fminf(bh * 0.5f + oy, bh * 0.5f - oy));
      valid = (m > 0.f);
    }
    if (valid) {
      float inter = inter_area(&g_hn_cor[h * 8], &g_pos_cor[j * 8]);
      float iou = inter / (g_hn_area[h] + g_pos_area[j] - inter + 1e-8f);
      valid = (iou >= 0.6f);
    }
    if (valid) {
      anyv = 1.f;
      float w = g_pv[j];
      wsum = w;
#pragma unroll
      for (int k = 0; k < 5; k++) wb[k] = w * g_pos_bbox[j * 5 + k];
    }
  }
  __syncthreads();
  red[0][j] = wsum;
#pragma unroll
  for (int k = 0; k < 5; k++) red[1 + k][j] = wb[k];
  red[6][j] = anyv;
  __syncthreads();
  for (int st = 128; st > 0; st >>= 1) {
    if (j < st)
#pragma unroll
      for (int k = 0; k < 7; k++) red[k][j] += red[k][j + st];
    __syncthreads();
  }
  if (j == 0 && hv && red[6][0] > 0.f) {
    float inv = 1.f / fmaxf(red[0][0], 1e-8f);
    float bb[5];
#pragma unroll
    for (int k = 0; k < 5; k++) bb[k] = red[1 + k][0] * inv;
    float ca = cosf(bb[4]), sa = sinf(bb[4]);
    float dx = g_hn_px[h] - bb[0], dy = g_hn_py[h] - bb[1];
    float ox = ca * dx + sa * dy, oy = -sa * dx + ca * dy;
    int m = g_hidx[h];
    g_loc_targets[m * 5 + 0] = bb[2] * 0.5f + ox;
    g_loc_targets[m * 5 + 1] = bb[3] * 0.5f + oy;
    g_loc_targets[m * 5 + 2] = bb[2] * 0.5f - ox;
    g_loc_targets[m * 5 + 3] = bb[3] * 0.5f - oy;
    g_loc_targets[m * 5 + 4] = bb[4];
    g_hnflag[m] = 1;
  }
  __syncthreads();
}

__device__ void loss_tile(int t, const InPtrs& P, float red[6][256]) {
  int tid = threadIdx.x;
  int n = t * 256 + tid;
  float v0, v1, v2, v3, v4, v5;
  {
    int lvl, idx, hw; float px, py;
    point_info(n, lvl, idx, hw, px, py);
    int pm = g_pos_mask[n], hm = g_hn_mask[n], hf = g_hnflag[n];
    int sel = pm | hm;
    bool lp = (pm | hf) != 0;
    float ctmax = sel ? g_sig_cls_max[n] : 0.f;
    const float* tcls = P.p[lvl * 4 + 0];
    const float* tbox = P.p[lvl * 4 + 1];
    const float* tang = P.p[lvl * 4 + 2];
    const float* scls = P.p[20 + lvl * 4 + 0];
    const float* sbox = P.p[20 + lvl * 4 + 1];
    const float* sang = P.p[20 + lvl * 4 + 2];
    const float* sctr = P.p[20 + lvl * 4 + 3];
    float siou = sigmoidf(sctr[idx]);
    float scl = 0.f;
    for (int c = 0; c < NCLS; c++) {
      float jc = sigmoidf(scls[c * hw + idx]) * siou;
      float ct = sel ? sigmoidf(tcls[c * hw + idx]) : 0.f;
      float p = jc;
      if (p < 1e-12f) p = 1e-12f;
      float pu = 1.f - 1e-12f;
      if (p > pu) p = pu;
      float bce = -(ct * logf(p) + (1.f - ct) * log1pf(-p));
      float d = fabsf(jc - ct);
      scl += bce * d * d;
    }
    v0 = scl;
    float lw = lp ? ctmax : 0.f;
    float tgt[5];
    if (hf) {
#pragma unroll
      for (int k = 0; k < 5; k++) tgt[k] = g_loc_targets[n * 5 + k];
    } else if (pm) {
      tgt[0] = tbox[idx]; tgt[1] = tbox[hw + idx];
      tgt[2] = tbox[2 * hw + idx]; tgt[3] = tbox[3 * hw + idx];
      tgt[4] = tang[idx];
    } else {
#pragma unroll
      for (int k = 0; k < 5; k++) tgt[k] = 0.f;
    }
    float sb = 0.f;
#pragma unroll
    for (int k = 0; k < 5; k++) {
      float sv = (k < 4) ? sbox[k * hw + idx] : sang[idx];
      float d = fabsf(sv - tgt[k]);
      sb += (d < 1.f) ? 0.5f * d * d : d - 0.5f;
    }
    v1 = sb * lw;
    v2 = 0.f;
    if (lp) {
      float p = siou;
      if (p < 1e-12f) p = 1e-12f;
      float pu = 1.f - 1e-12f;
      if (p > pu) p = pu;
      float ti = g_sig_tiou[n];
      v2 = -(ti * logf(p) + (1.f - ti) * log1pf(-p));
    }
    v3 = pm ? ctmax : 0.f;   // cls_avg
    v4 = lw;                 // loc_avg
    v5 = lp ? 1.f : 0.f;     // iou_avg
  }
  __syncthreads();
  red[0][tid] = v0; red[1][tid] = v1; red[2][tid] = v2;
  red[3][tid] = v3; red[4][tid] = v4; red[5][tid] = v5;
  __syncthreads();
  for (int st = 128; st > 0; st >>= 1) {
    if (tid < st)
#pragma unroll
      for (int k = 0; k < 6; k++) red[k][tid] += red[k][tid + st];
    __syncthreads();
  }
  if (tid == 0)
#pragma unroll
    for (int k = 0; k < 6; k++) g_partials[t * 6 + k] = red[k][0];
}

__device__ void final_reduce(float* out, float red[6][256]) {
  int tid = threadIdx.x;
  float a[6] = {0,0,0,0,0,0};
  for (int i = tid; i < TILES; i += 256)
#pragma unroll
    for (int k = 0; k < 6; k++) a[k] += g_partials[i * 6 + k];
  __syncthreads();
#pragma unroll
  for (int k = 0; k < 6; k++) red[k][tid] = a[k];
  __syncthreads();
  for (int st = 128; st > 0; st >>= 1) {
    if (tid < st)
#pragma unroll
      for (int k = 0; k < 6; k++) red[k][tid] += red[k][tid + st];
    __syncthreads();
  }
  if (tid == 0) {
    out[0] = red[0][0] / fmaxf(red[3][0], 1e-8f);
    out[1] = red[1][0] / fmaxf(red[4][0], 1e-8f);
    out[2] = red[2][0] / fmaxf(red[5][0], 1.f);
  }
}

// ======================= single fused kernel (flag-array grid barrier) =======================
__global__ __launch_bounds__(256) void k_fused(InPtrs P, float* out) {
  const int tid = threadIdx.x;
  const int b = blockIdx.x;
  const int G = gridDim.x;

  __shared__ float red7[7][256];
  __shared__ int   si0[256], si1[256];
  __shared__ int   hist[256];
  __shared__ int   sh_i[2];

  // Phase A
  for (int t = b; t < TILES; t += G) phaseA_tile(t, P, (float(*)[256])red7);
  gridbar();

  // Phase B: threshold (redundant per block) + masks
  {
    float th = compute_thresh((float(*)[256])red7, si0);
    for (int t = b; t < TILES; t += G) phaseB_tile(t, th, si0, si1);
  }
  gridbar();

  // Phase C: totals + compaction
  int tp, thn, fallback;
  totals_tphn(si0, si1, tp, thn);
  fallback = (tp == 0) ? 1 : 0;
  for (int t = b; t < TILES; t += G) phaseC_tile(t, si0, si1);
  gridbar();

  // Phase D (rare): slow selection by block 0
  const bool slow = fallback || tp > KPOS || thn > KHN;
  if (slow) {
    if (b == 0) slow_select_block(tp, thn, fallback, hist, si0, si1, sh_i);
    gridbar();
  }

  // Phase E: fast select + decode (global thread id covers KPOS+KHN = 2304)
  decode_slot(b * 256 + tid, P, slow, tp, thn);
  gridbar();

  // Phase F: IoU + aggregation + scatter
  for (int h = b; h < KHN; h += G) iou_hn(h, (float(*)[256])red7);
  gridbar();

  // Phase G: per-point losses
  for (int t = b; t < TILES; t += G) loss_tile(t, P, (float(*)[256])red7);
  gridbar();

  // Phase H: final reduce
  if (b == 0) final_reduce(out, (float(*)[256])red7);
}

// ======================= fallback multi-kernel chain (proven R3 path) =======================
__global__ __launch_bounds__(256) void k_prep(InPtrs P) {
  __shared__ float red[3][256];
  phaseA_tile(blockIdx.x, P, red);
}
__global__ __launch_bounds__(256) void k_mask() {
  __shared__ float red[2][256];
  __shared__ int si0[256], si1[256];
  float th = compute_thresh(red, si0);
  phaseB_tile(blockIdx.x, th, si0, si1);
}
__global__ __launch_bounds__(256) void k_compact() {
  __shared__ int si0[256], si1[256];
  int tp, thn;
  totals_tphn(si0, si1, tp, thn);
  if (blockIdx.x == 0 && threadIdx.x == 0) {
    g_total_pos = tp; g_total_hn = thn; g_fallback = (tp == 0) ? 1 : 0;
  }
  phaseC_tile(blockIdx.x, si0, si1);
}
__global__ __launch_bounds__(256) void k_select() {
  __shared__ int hist[256], si0[256], si1[256], sh_i[2];
  int tp = g_total_pos, thn = g_total_hn, fallback = g_fallback;
  bool slow = fallback || tp > KPOS || thn > KHN;
  if (slow) {
    slow_select_block(tp, thn, fallback, hist, si0, si1, sh_i);
  } else {
    int tid = threadIdx.x;
    for (int i = tid; i < KPOS; i += 256) {
      int v = (i < tp) ? 1 : 0;
      int m = v ? g_pos_cand[i] : 0;
      g_pvalid[i] = v; g_pidx[i] = m; g_pv[i] = v ? g_max_vals[m] : -1.f;
    }
    for (int i = tid; i < KHN; i += 256) {
      int v = (i < thn) ? 1 : 0;
      g_hvalid[i] = v; g_hidx[i] = v ? g_hn_cand[i] : 0;
    }
  }
}
__global__ __launch_bounds__(256) void k_decode(InPtrs P) {
  decode_slot(blockIdx.x * 256 + threadIdx.x, P, true, 0, 0);
}
__global__ __launch_bounds__(256) void k_iou() {
  __shared__ float red[7][256];
  iou_hn(blockIdx.x, red);
}
__global__ __launch_bounds__(256) void k_loss(InPtrs P) {
  __shared__ float red[6][256];
  loss_tile(blockIdx.x, P, red);
}
__global__ __launch_bounds__(256) void k_final(float* out) {
  __shared__ float red[6][256];
  final_reduce(out, red);
}

extern "C" void kernel_launch(void* const* d_in, const int* in_sizes, int n_in,
                              void* d_out, int out_size, void* d_ws, size_t ws_size,
                              hipStream_t stream) {
  (void)in_sizes; (void)n_in; (void)out_size; (void)d_ws; (void)ws_size;
  InPtrs P;
  for (int i = 0; i < 40; i++) P.p[i] = (const float*)d_in[i];
  float* outp = (float*)d_out;
  void* args[] = { (void*)&P, (void*)&outp };
  hipError_t err = hipLaunchCooperativeKernel((const void*)k_fused, dim3(MAXG), dim3(256),
                                              args, 0, stream);
  if (err != hipSuccess) {
    (void)hipGetLastError();
    err = hipLaunchCooperativeKernel((const void*)k_fused, dim3(256), dim3(256),
                                     args, 0, stream);
  }
  if (err != hipSuccess) {
    (void)hipGetLastError();  // clear sticky error, take the multi-kernel path
    k_prep<<<TILES, 256, 0, stream>>>(P);
    k_mask<<<TILES, 256, 0, stream>>>();
    k_compact<<<TILES, 256, 0, stream>>>();
    k_select<<<1, 256, 0, stream>>>();
    k_decode<<<(KPOS + KHN + 255) / 256, 256, 0, stream>>>(P);
    k_iou<<<KHN, 256, 0, stream>>>();
    k_loss<<<TILES, 256, 0, stream>>>(P);
    k_final<<<1, 256, 0, stream>>>((float*)d_out);
  }
}

// Round 9
// 154.929 us; speedup vs baseline: 6021.9268x; 6021.9268x over previous
//
#include <hip/hip_runtime.h>
#include <math.h>

#define NPTS 87296
#define NCLS 16
#define KPOS 256
#define KHN  2048
#define TILES 341           // NPTS / 256 exactly
#define CAP  4096           // compacted-candidate capacity (slow path beyond)
#define PI_F   3.14159265358979323846f
#define HPI_F  1.57079632679489661923f

struct InPtrs { const float* p[40]; };
// input index = pre*20 + lvl*4 + {cls:0, box:1, ang:2, ctr:3}; pre: t=0, s=1

// ---------------- persistent device scratch (rewritten every call) ----------------
__device__ float g_max_vals[NPTS];
__device__ float g_sig_tiou[NPTS];
__device__ float g_sig_cls_max[NPTS];
__device__ int   g_class_ind[NPTS];
__device__ int   g_pos_mask[NPTS];
__device__ int   g_hn_mask[NPTS];
__device__ int   g_hnflag[NPTS];          // 1 = loc target overridden by aggregated hn
__device__ float g_loc_targets[NPTS * 5]; // only hn slots are written/read
__device__ float g_bsum[TILES];
__device__ float g_bsumsq[TILES];
__device__ int   g_bcnt[TILES];
__device__ float g_thresh;
__device__ int   g_tp, g_thn, g_slow;
__device__ int   g_pos_cand[CAP];
__device__ int   g_hn_cand[CAP];
__device__ int   g_pidx[KPOS];
__device__ int   g_pvalid[KPOS];
__device__ float g_pv[KPOS];
__device__ int   g_hidx[KHN];
__device__ int   g_hvalid[KHN];
__device__ float g_partials[TILES * 6];
// monotonic last-done epoch counters (never reset; survive graph replays)
__device__ unsigned long long g_done_prep = 0ull;
__device__ unsigned long long g_done_cmp  = 0ull;
__device__ unsigned long long g_done_loss = 0ull;

// ---------------- helpers ----------------
__device__ __forceinline__ float sigmoidf(float x) {
  if (x >= 0.f) return 1.f / (1.f + expf(-x));
  float e = expf(x);
  return e / (1.f + e);
}
__device__ __forceinline__ float crs(float ax, float ay, float bx, float by) {
  return ax * by - ay * bx;
}
__device__ __forceinline__ float mod_pos(float x, float y) {
  float r = fmodf(x, y);
  if (r < 0.f) r += y;
  return r;
}
// monotonic pseudo-angle: strictly increasing map of atan2(dy,dx) -> (-2,2]
__device__ __forceinline__ float pseudo_ang(float dx, float dy) {
  float den = fabsf(dx) + fabsf(dy);
  if (den == 0.f) return 0.f;         // matches atan2(0,0)=0 tie class
  return copysignf(1.f - dx / den, dy);
}
__device__ __forceinline__ void point_info(int n, int& lvl, int& idx, int& hw,
                                           float& px, float& py) {
  int off, wsh; float stride;
  if (n < 65536)      { lvl = 0; off = 0;     wsh = 8; stride = 8.f;   hw = 65536; }
  else if (n < 81920) { lvl = 1; off = 65536; wsh = 7; stride = 16.f;  hw = 16384; }
  else if (n < 86016) { lvl = 2; off = 81920; wsh = 6; stride = 32.f;  hw = 4096; }
  else if (n < 87040) { lvl = 3; off = 86016; wsh = 5; stride = 64.f;  hw = 1024; }
  else                { lvl = 4; off = 87040; wsh = 4; stride = 128.f; hw = 256; }
  idx = n - off;
  int y = idx >> wsh, x = idx & ((1 << wsh) - 1);
  px = ((float)x + 0.5f) * stride;
  py = ((float)y + 0.5f) * stride;
}

// ---------------- radix select paths (rare; 256-thread block variants) ----------------
#define MASK_ALL 0
#define MASK_POS 1
#define MASK_HN  2
__device__ __forceinline__ int sel_mask(int mode, int n) {
  return mode == MASK_ALL ? 1 : (mode == MASK_POS ? g_pos_mask[n] : g_hn_mask[n]);
}

__device__ void radix_select_mask(int mode, int K, int* out_idx, int* out_valid, float* out_val,
                                  int* hist, int* scan_a, int* scan_b, int* sh) {
  int tid = threadIdx.x;
  int c = 0;
  for (int n = tid; n < NPTS; n += 256) if (sel_mask(mode, n)) c++;
  scan_a[tid] = c; __syncthreads();
  for (int st = 128; st > 0; st >>= 1) {
    if (tid < st) scan_a[tid] += scan_a[tid + st];
    __syncthreads();
  }
  int total = scan_a[0];
  __syncthreads();

  unsigned kth = 0u;
  if (total > K) {
    unsigned prefix = 0; int rem = K;
    for (int pass = 0; pass < 4; pass++) {
      int shift = 24 - 8 * pass;
      hist[tid] = 0;
      __syncthreads();
      for (int n = tid; n < NPTS; n += 256) {
        if (sel_mask(mode, n)) {
          unsigned k = __float_as_uint(g_max_vals[n]);
          if (pass == 0 || ((k >> (shift + 8)) == prefix))
            atomicAdd(&hist[(k >> shift) & 255], 1);
        }
      }
      __syncthreads();
      if (tid == 0) {
        int cum = 0, b = 255;
        for (; b > 0; b--) {
          if (cum + hist[b] >= rem) break;
          cum += hist[b];
        }
        sh[0] = (int)((prefix << 8) | (unsigned)b);
        sh[1] = rem - cum;
      }
      __syncthreads();
      prefix = (unsigned)sh[0]; rem = sh[1];
      __syncthreads();
    }
    kth = prefix;
  }

  const int chunk = (NPTS + 255) / 256;
  int start = tid * chunk; if (start > NPTS) start = NPTS;
  int end = start + chunk; if (end > NPTS) end = NPTS;
  int cgt = 0, ceq = 0;
  for (int n = start; n < end; n++) {
    if (sel_mask(mode, n)) {
      unsigned k = __float_as_uint(g_max_vals[n]);
      if (k > kth) cgt++;
      else if (k == kth) ceq++;
    }
  }
  scan_a[tid] = cgt; scan_b[tid] = ceq; __syncthreads();
  if (tid == 0) {
    int ag = 0, ae = 0;
    for (int i = 0; i < 256; i++) {
      int tg = scan_a[i], te = scan_b[i];
      scan_a[i] = ag; scan_b[i] = ae;
      ag += tg; ae += te;
    }
    sh[0] = ag; sh[1] = ae;
  }
  __syncthreads();
  int cnt_gt = sh[0], cnt_eq = sh[1];
  int og = scan_a[tid], oe = cnt_gt + scan_b[tid];
  for (int n = start; n < end; n++) {
    if (sel_mask(mode, n)) {
      unsigned k = __float_as_uint(g_max_vals[n]);
      if (k > kth) {
        out_idx[og] = n; out_valid[og] = 1;
        if (out_val) out_val[og] = g_max_vals[n];
        og++;
      } else if (k == kth) {
        if (oe < K) {
          out_idx[oe] = n; out_valid[oe] = 1;
          if (out_val) out_val[oe] = g_max_vals[n];
        }
        oe++;
      }
    }
  }
  int kmc = K - cnt_gt;
  int used = cnt_gt + (cnt_eq < kmc ? cnt_eq : kmc);
  __syncthreads();
  for (int i = used + tid; i < K; i += 256) {
    out_idx[i] = 0; out_valid[i] = 0;
    if (out_val) out_val[i] = -1.f;
  }
  __syncthreads();
}

__device__ void radix_select_list(const int* list, int count, int K,
                                  int* out_idx, int* out_valid, float* out_val,
                                  int* hist, int* scan_a, int* scan_b, int* sh) {
  // requires count > K
  int tid = threadIdx.x;
  unsigned prefix = 0; int rem = K;
  for (int pass = 0; pass < 4; pass++) {
    int shift = 24 - 8 * pass;
    hist[tid] = 0;
    __syncthreads();
    for (int i = tid; i < count; i += 256) {
      unsigned k = __float_as_uint(g_max_vals[list[i]]);
      if (pass == 0 || ((k >> (shift + 8)) == prefix))
        atomicAdd(&hist[(k >> shift) & 255], 1);
    }
    __syncthreads();
    if (tid == 0) {
      int cum = 0, b = 255;
      for (; b > 0; b--) {
        if (cum + hist[b] >= rem) break;
        cum += hist[b];
      }
      sh[0] = (int)((prefix << 8) | (unsigned)b);
      sh[1] = rem - cum;
    }
    __syncthreads();
    prefix = (unsigned)sh[0]; rem = sh[1];
    __syncthreads();
  }
  unsigned kth = prefix;
  int chunk = (count + 255) / 256;
  int start = tid * chunk; if (start > count) start = count;
  int end = start + chunk; if (end > count) end = count;
  int cgt = 0, ceq = 0;
  for (int i = start; i < end; i++) {
    unsigned k = __float_as_uint(g_max_vals[list[i]]);
    if (k > kth) cgt++;
    else if (k == kth) ceq++;
  }
  scan_a[tid] = cgt; scan_b[tid] = ceq; __syncthreads();
  if (tid == 0) {
    int ag = 0, ae = 0;
    for (int i = 0; i < 256; i++) {
      int tg = scan_a[i], te = scan_b[i];
      scan_a[i] = ag; scan_b[i] = ae;
      ag += tg; ae += te;
    }
    sh[0] = ag;
  }
  __syncthreads();
  int cnt_gt = sh[0];
  int og = scan_a[tid], oe = cnt_gt + scan_b[tid];
  for (int i = start; i < end; i++) {
    int n = list[i];
    unsigned k = __float_as_uint(g_max_vals[n]);
    if (k > kth) {
      out_idx[og] = n; out_valid[og] = 1;
      if (out_val) out_val[og] = g_max_vals[n];
      og++;
    } else if (k == kth) {
      if (oe < K) {
        out_idx[oe] = n; out_valid[oe] = 1;
        if (out_val) out_val[oe] = g_max_vals[n];
      }
      oe++;
    }
  }
  __syncthreads();
}

__device__ void slow_select_block(int tp, int thn, int fallback,
                                  int* hist, int* si0, int* si1, int* sh_i) {
  int tid = threadIdx.x;
  if (!fallback && tp <= KPOS) {
    for (int i = tid; i < KPOS; i += 256) {
      if (i < tp) {
        int m = g_pos_cand[i];
        g_pidx[i] = m; g_pvalid[i] = 1; g_pv[i] = g_max_vals[m];
      } else { g_pidx[i] = 0; g_pvalid[i] = 0; g_pv[i] = -1.f; }
    }
    __syncthreads();
  } else if (!fallback && tp <= CAP) {
    radix_select_list(g_pos_cand, tp, KPOS, g_pidx, g_pvalid, g_pv, hist, si0, si1, sh_i);
  } else if (!fallback) {
    radix_select_mask(MASK_POS, KPOS, g_pidx, g_pvalid, g_pv, hist, si0, si1, sh_i);
  } else {
    radix_select_mask(MASK_ALL, 10, g_pidx, g_pvalid, g_pv, hist, si0, si1, sh_i);
    for (int i = tid; i < 10; i += 256)
      if (g_pvalid[i]) g_pos_mask[g_pidx[i]] = 1;
    for (int i = 10 + tid; i < KPOS; i += 256) {
      g_pidx[i] = 0; g_pvalid[i] = 0; g_pv[i] = -1.f;
    }
    __syncthreads();
  }
  if (thn <= KHN) {
    for (int i = tid; i < KHN; i += 256) {
      if (i < thn) { g_hidx[i] = g_hn_cand[i]; g_hvalid[i] = 1; }
      else { g_hidx[i] = 0; g_hvalid[i] = 0; }
    }
  } else if (thn <= CAP) {
    radix_select_list(g_hn_cand, thn, KHN, g_hidx, g_hvalid, (float*)0, hist, si0, si1, sh_i);
  } else {
    radix_select_mask(MASK_HN, KHN, g_hidx, g_hvalid, (float*)0, hist, si0, si1, sh_i);
  }
}

// ---------------- decode helper ----------------
__device__ void decode_box(int n, const InPtrs& P, float* bb, float* cor,
                           float& area, float& scale, int& cls_out,
                           float* opx, float* opy) {
  int lvl, idx, hw; float px, py;
  point_info(n, lvl, idx, hw, px, py);
  const float* box = P.p[lvl * 4 + 1];
  const float* ang = P.p[lvl * 4 + 2];
  float l = box[idx], t = box[hw + idx], r = box[2 * hw + idx], b = box[3 * hw + idx];
  float a = ang[idx];
  float ca = cosf(a), sa = sinf(a);
  float w = l + r, h = t + b;
  float oxl = (r - l) * 0.5f, oyl = (b - t) * 0.5f;
  float ox = ca * oxl - sa * oyl;
  float oy = sa * oxl + ca * oyl;
  float an = mod_pos(a + HPI_F, PI_F) - HPI_F;
  float cx = px + ox, cy = py + oy;
  bb[0] = cx; bb[1] = cy; bb[2] = w; bb[3] = h; bb[4] = an;
  float c2 = cosf(an), s2 = sinf(an);
  const float dxs[4] = {-0.5f, 0.5f, 0.5f, -0.5f};
  const float dys[4] = {-0.5f, -0.5f, 0.5f, 0.5f};
#pragma unroll
  for (int k = 0; k < 4; k++) {
    float dx = dxs[k] * w, dy = dys[k] * h;
    cor[2 * k]     = cx + dx * c2 - dy * s2;
    cor[2 * k + 1] = cy + dx * s2 + dy * c2;
  }
  area = fabsf(w * h);
  scale = (float)lvl;
  cls_out = g_class_ind[n];
  if (opx) { *opx = px; *opy = py; }
}

// ---------------- convex quad intersection — fully register-resident ----------------
#define BPASS(KK, JJ)                                                      \
  _Pragma("unroll")                                                        \
  for (int i = 0; i < 32; i++) {                                           \
    int l = i ^ (JJ);                                                      \
    if (l > i) {                                                           \
      bool up = ((i & (KK)) == 0);                                         \
      float aa = sa_[i], ab = sa_[l];                                      \
      bool sw = up ? (aa > ab) : (aa < ab);                                \
      sa_[i] = sw ? ab : aa; sa_[l] = sw ? aa : ab;                        \
      float xi = sx_[i], xl = sx_[l];                                      \
      sx_[i] = sw ? xl : xi; sx_[l] = sw ? xi : xl;                        \
      float yi = sy_[i], yl = sy_[l];                                      \
      sy_[i] = sw ? yl : yi; sy_[l] = sw ? yi : yl;                        \
    }                                                                      \
  }

__device__ float inter_area(const float* __restrict__ A, const float* __restrict__ B) {
  float ax[4], ay[4], bx[4], by[4];
#pragma unroll
  for (int i = 0; i < 4; i++) {
    ax[i] = A[2 * i]; ay[i] = A[2 * i + 1];
    bx[i] = B[2 * i]; by[i] = B[2 * i + 1];
  }
  float dax[4], day[4], dbx[4], dby[4];
#pragma unroll
  for (int i = 0; i < 4; i++) {
    int i1 = (i + 1) & 3;
    dax[i] = ax[i1] - ax[i]; day[i] = ay[i1] - ay[i];
    dbx[i] = bx[i1] - bx[i]; dby[i] = by[i1] - by[i];
  }
  float px[24], py[24]; bool val[24];
#pragma unroll
  for (int i = 0; i < 4; i++) {
#pragma unroll
    for (int j = 0; j < 4; j++) {
      float dx = bx[j] - ax[i], dy = by[j] - ay[i];
      float den = crs(dax[i], day[i], dbx[j], dby[j]);
      float ad = fabsf(den);
      float ds = (ad < 1e-10f) ? 1.0f : den;
      float t = crs(dx, dy, dbx[j], dby[j]) / ds;
      float u = crs(dx, dy, dax[i], day[i]) / ds;
      bool ok = (ad > 1e-10f) & (t >= 0.f) & (t <= 1.f) & (u >= 0.f) & (u <= 1.f);
      int k = i * 4 + j;
      px[k] = ax[i] + t * dax[i];
      py[k] = ay[i] + t * day[i];
      val[k] = ok;
    }
  }
#pragma unroll
  for (int i = 0; i < 4; i++) {   // corners of A inside B
    bool ge = true, le = true;
#pragma unroll
    for (int j = 0; j < 4; j++) {
      float s = crs(dbx[j], dby[j], ax[i] - bx[j], ay[i] - by[j]);
      ge = ge && (s >= -1e-9f);
      le = le && (s <= 1e-9f);
    }
    val[16 + i] = ge || le; px[16 + i] = ax[i]; py[16 + i] = ay[i];
  }
#pragma unroll
  for (int j = 0; j < 4; j++) {   // corners of B inside A
    bool ge = true, le = true;
#pragma unroll
    for (int i = 0; i < 4; i++) {
      float s = crs(dax[i], day[i], bx[j] - ax[i], by[j] - ay[i]);
      ge = ge && (s >= -1e-9f);
      le = le && (s <= 1e-9f);
    }
    val[20 + j] = ge || le; px[20 + j] = bx[j]; py[20 + j] = by[j];
  }
  int n = 0; float sx = 0.f, sy = 0.f;
#pragma unroll
  for (int k = 0; k < 24; k++) if (val[k]) { n++; sx += px[k]; sy += py[k]; }
  float dn = (float)(n > 1 ? n : 1);
  float cx = sx / dn, cy = sy / dn;

  // 24 real slots (invalid collapse to centroid) + 8 +INF dummies; non-stable
  // network OK: angle ties only among identical centroid points (zero terms).
  float sa_[32], sx_[32], sy_[32];
#pragma unroll
  for (int k = 0; k < 24; k++) {
    float X = val[k] ? px[k] : cx;
    float Y = val[k] ? py[k] : cy;
    sx_[k] = X; sy_[k] = Y;
    sa_[k] = pseudo_ang(X - cx, Y - cy);
  }
#pragma unroll
  for (int k = 24; k < 32; k++) {
    sa_[k] = __int_as_float(0x7f800000);  // +inf
    sx_[k] = cx; sy_[k] = cy;
  }
  BPASS(2, 1)
  BPASS(4, 2)  BPASS(4, 1)
  BPASS(8, 4)  BPASS(8, 2)  BPASS(8, 1)
  BPASS(16, 8) BPASS(16, 4) BPASS(16, 2) BPASS(16, 1)
  BPASS(32, 16) BPASS(32, 8) BPASS(32, 4) BPASS(32, 2) BPASS(32, 1)

  float s2 = 0.f;
#pragma unroll
  for (int k = 0; k < 24; k++) {
    int k1 = (k + 1) % 24;
    s2 += crs(sx_[k] - cx, sy_[k] - cy, sx_[k1] - cx, sy_[k1] - cy);
  }
  float area = 0.5f * fabsf(s2);
  return (n >= 3) ? area : 0.f;
}

// ================= kernel 1: per-point stats + partials; last block -> threshold =================
__global__ __launch_bounds__(256) void k_prep(InPtrs P) {
  int tid = threadIdx.x;
  int t = blockIdx.x;
  int n = t * 256 + tid;
  __shared__ float r0[256], r1[256], r2[256];
  __shared__ int   si0[256];
  __shared__ int   s_last;

  int lvl, idx, hw; float px, py;
  point_info(n, lvl, idx, hw, px, py);
  const float* cls = P.p[lvl * 4 + 0];
  const float* ctr = P.p[lvl * 4 + 3];
  float stiou = sigmoidf(ctr[idx]);
  float mv = -1.f, scm = 0.f; int ci = 0;
  for (int c = 0; c < NCLS; c++) {
    float sc = sigmoidf(cls[c * hw + idx]);
    if (sc > scm) scm = sc;
    float j = sc * stiou;
    if (j > mv) { mv = j; ci = c; }
  }
  g_max_vals[n] = mv;
  g_class_ind[n] = ci;
  g_sig_tiou[n] = stiou;
  g_sig_cls_max[n] = scm;
  g_hnflag[n] = 0;
  float isc = (mv >= 0.1f) ? 1.f : 0.f;
  r0[tid] = isc; r1[tid] = isc * mv; r2[tid] = isc * mv * mv;
  __syncthreads();
  for (int st = 128; st > 0; st >>= 1) {
    if (tid < st) { r0[tid] += r0[tid + st]; r1[tid] += r1[tid + st]; r2[tid] += r2[tid + st]; }
    __syncthreads();
  }
  if (tid == 0) {
    g_bcnt[t] = (int)r0[0];
    g_bsum[t] = r1[0];
    g_bsumsq[t] = r2[0];
  }
  // last-done block computes the threshold (no spinning: single coherent RMW)
  __threadfence();
  if (tid == 0) {
    unsigned long long v = atomicAdd(&g_done_prep, 1ull);
    s_last = ((v % (unsigned long long)TILES) == (unsigned long long)(TILES - 1)) ? 1 : 0;
  }
  __syncthreads();
  if (s_last) {
    __threadfence();
    int c = 0; float s = 0.f, q = 0.f;
    for (int i = tid; i < TILES; i += 256) { c += g_bcnt[i]; s += g_bsum[i]; q += g_bsumsq[i]; }
    __syncthreads();
    si0[tid] = c; r0[tid] = s; r1[tid] = q; __syncthreads();
    for (int st = 128; st > 0; st >>= 1) {
      if (tid < st) { si0[tid] += si0[tid + st]; r0[tid] += r0[tid + st]; r1[tid] += r1[tid + st]; }
      __syncthreads();
    }
    if (tid == 0) {
      int nc = si0[0]; float sum = r0[0], sumsq = r1[0];
      float mean = sum / (float)(nc > 1 ? nc : 1);
      float E = sumsq - 2.f * mean * sum + (float)nc * mean * mean;
      if (E < 0.f) E = 0.f;
      float var = E / (float)((nc - 1) > 1 ? (nc - 1) : 1);
      float th = fminf(mean + sqrtf(var), 0.4f);
      if (nc == 0) th = __int_as_float(0x7f800000);  // +inf
      g_thresh = th;
    }
  }
}

// ============ kernel 2: masks + prefix-by-rescan + compaction; last block -> totals/slow-select ============
__global__ __launch_bounds__(256) void k_maskcompact() {
  int tid = threadIdx.x;
  int t = blockIdx.x;
  int n = t * 256 + tid;
  __shared__ int si0[256], si1[256];
  __shared__ int hist[256];
  __shared__ int sh_i[2];
  __shared__ int s_last;

  float th = g_thresh;
  float v = g_max_vals[n];
  int pm = (v >= th) ? 1 : 0;
  int hm = (v >= 0.1f && v < th) ? 1 : 0;
  g_pos_mask[n] = pm; g_hn_mask[n] = hm;

  // exclusive prefix over points [0, t*256) by predicate re-scan (L2-resident)
  int cp = 0, ch = 0;
  int lim = t * 256;
  for (int i = tid; i < lim; i += 256) {
    float u = g_max_vals[i];
    cp += (u >= th) ? 1 : 0;
    ch += (u >= 0.1f && u < th) ? 1 : 0;
  }
  si0[tid] = cp; si1[tid] = ch; __syncthreads();
  for (int st = 128; st > 0; st >>= 1) {
    if (tid < st) { si0[tid] += si0[tid + st]; si1[tid] += si1[tid + st]; }
    __syncthreads();
  }
  int poff = si0[0], hoff = si1[0];
  __syncthreads();

  // in-tile inclusive scan of masks
  si0[tid] = pm; si1[tid] = hm; __syncthreads();
  for (int off = 1; off < 256; off <<= 1) {
    int ap = (tid >= off) ? si0[tid - off] : 0;
    int ah = (tid >= off) ? si1[tid - off] : 0;
    __syncthreads();
    si0[tid] += ap; si1[tid] += ah;
    __syncthreads();
  }
  if (pm) { int o = poff + si0[tid] - pm; if (o < CAP) g_pos_cand[o] = n; }
  if (hm) { int o = hoff + si1[tid] - hm; if (o < CAP) g_hn_cand[o] = n; }
  // tile that owns the LAST tile publishes totals
  if (t == TILES - 1 && tid == 255) {
    g_tp = poff + si0[255];
    g_thn = hoff + si1[255];
  }

  // last-done block decides slow/fallback and runs the (rare) radix select
  __threadfence();
  if (tid == 0) {
    unsigned long long dv = atomicAdd(&g_done_cmp, 1ull);
    s_last = ((dv % (unsigned long long)TILES) == (unsigned long long)(TILES - 1)) ? 1 : 0;
  }
  __syncthreads();
  if (s_last) {
    __threadfence();
    int tp = g_tp, thn = g_thn;
    int fallback = (tp == 0) ? 1 : 0;
    int slow = (fallback || tp > KPOS || thn > KHN) ? 1 : 0;
    if (tid == 0) g_slow = slow;
    __syncthreads();
    if (slow) slow_select_block(tp, thn, fallback, hist, si0, si1, sh_i);
  }
}

// ============ kernel 3: IoU + aggregation + scatter, with inline select + decode ============
__global__ __launch_bounds__(256) void k_iou(InPtrs P) {
  const int h = blockIdx.x;
  const int j = threadIdx.x;
  const int slow = g_slow;
  const int tp = g_tp, thn = g_thn;

  const int hv = slow ? g_hvalid[h] : ((h < thn) ? 1 : 0);
  if (!hv) return;   // block-uniform
  const int nh = slow ? g_hidx[h] : g_hn_cand[h];

  // redundant per-thread hn decode (cheap; keeps everything in registers)
  float hbb[5], hcor[8], har, hsc, hpx, hpy; int hcl;
  decode_box(nh, P, hbb, hcor, har, hsc, hcl, &hpx, &hpy);

  float wsum = 0.f, wb[5] = {0,0,0,0,0}, anyv = 0.f;
  const int pvld = slow ? g_pvalid[j] : ((j < tp) ? 1 : 0);
  if (pvld) {
    int m = slow ? g_pidx[j] : g_pos_cand[j];
    float pv = slow ? g_pv[j] : g_max_vals[m];
    float pbb[5], pcor[8], par, psc; int pcl;
    decode_box(m, P, pbb, pcor, par, psc, pcl, (float*)0, (float*)0);
    bool valid = (pcl == hcl) && (fabsf(psc - hsc) <= 1.0f);
    if (valid) {
      float ca = cosf(pbb[4]), sa = sinf(pbb[4]);
      float dx = hpx - pbb[0], dy = hpy - pbb[1];
      float ox = ca * dx + sa * dy, oy = -sa * dx + ca * dy;
      float mm = fminf(fminf(pbb[2] * 0.5f + ox, pbb[2] * 0.5f - ox),
                       fminf(pbb[3] * 0.5f + oy, pbb[3] * 0.5f - oy));
      valid = (mm > 0.f);
    }
    if (valid) {
      float inter = inter_area(hcor, pcor);
      float iou = inter / (har + par - inter + 1e-8f);
      valid = (iou >= 0.6f);
    }
    if (valid) {
      anyv = 1.f; wsum = pv;
#pragma unroll
      for (int k = 0; k < 5; k++) wb[k] = pv * pbb[k];
    }
  }
  __shared__ float red[7][256];
  red[0][j] = wsum;
#pragma unroll
  for (int k = 0; k < 5; k++) red[1 + k][j] = wb[k];
  red[6][j] = anyv;
  __syncthreads();
  for (int st = 128; st > 0; st >>= 1) {
    if (j < st)
#pragma unroll
      for (int k = 0; k < 7; k++) red[k][j] += red[k][j + st];
    __syncthreads();
  }
  if (j == 0 && red[6][0] > 0.f) {
    float inv = 1.f / fmaxf(red[0][0], 1e-8f);
    float bb[5];
#pragma unroll
    for (int k = 0; k < 5; k++) bb[k] = red[1 + k][0] * inv;
    float ca = cosf(bb[4]), sa = sinf(bb[4]);
    float dx = hpx - bb[0], dy = hpy - bb[1];
    float ox = ca * dx + sa * dy, oy = -sa * dx + ca * dy;
    g_loc_targets[nh * 5 + 0] = bb[2] * 0.5f + ox;
    g_loc_targets[nh * 5 + 1] = bb[3] * 0.5f + oy;
    g_loc_targets[nh * 5 + 2] = bb[2] * 0.5f - ox;
    g_loc_targets[nh * 5 + 3] = bb[3] * 0.5f - oy;
    g_loc_targets[nh * 5 + 4] = bb[4];
    g_hnflag[nh] = 1;
  }
}

// ============ kernel 4: per-point losses -> partials; last block -> final + output ============
__global__ __launch_bounds__(256) void k_loss(InPtrs P, float* out) {
  int tid = threadIdx.x;
  int t = blockIdx.x;
  int n = t * 256 + tid;
  __shared__ float red[6][256];
  __shared__ int s_last;
  float v0, v1, v2, v3, v4, v5;
  {
    int lvl, idx, hw; float px, py;
    point_info(n, lvl, idx, hw, px, py);
    int pm = g_pos_mask[n], hm = g_hn_mask[n], hf = g_hnflag[n];
    int sel = pm | hm;
    bool lp = (pm | hf) != 0;
    float ctmax = sel ? g_sig_cls_max[n] : 0.f;
    const float* tcls = P.p[lvl * 4 + 0];
    const float* tbox = P.p[lvl * 4 + 1];
    const float* tang = P.p[lvl * 4 + 2];
    const float* scls = P.p[20 + lvl * 4 + 0];
    const float* sbox = P.p[20 + lvl * 4 + 1];
    const float* sang = P.p[20 + lvl * 4 + 2];
    const float* sctr = P.p[20 + lvl * 4 + 3];
    float siou = sigmoidf(sctr[idx]);
    float scl = 0.f;
    for (int c = 0; c < NCLS; c++) {
      float jc = sigmoidf(scls[c * hw + idx]) * siou;
      float ct = sel ? sigmoidf(tcls[c * hw + idx]) : 0.f;
      float p = jc;
      if (p < 1e-12f) p = 1e-12f;
      float pu = 1.f - 1e-12f;
      if (p > pu) p = pu;
      float bce = -(ct * logf(p) + (1.f - ct) * log1pf(-p));
      float d = fabsf(jc - ct);
      scl += bce * d * d;
    }
    v0 = scl;
    float lw = lp ? ctmax : 0.f;
    float tgt[5];
    if (hf) {
#pragma unroll
      for (int k = 0; k < 5; k++) tgt[k] = g_loc_targets[n * 5 + k];
    } else if (pm) {
      tgt[0] = tbox[idx]; tgt[1] = tbox[hw + idx];
      tgt[2] = tbox[2 * hw + idx]; tgt[3] = tbox[3 * hw + idx];
      tgt[4] = tang[idx];
    } else {
#pragma unroll
      for (int k = 0; k < 5; k++) tgt[k] = 0.f;
    }
    float sb = 0.f;
#pragma unroll
    for (int k = 0; k < 5; k++) {
      float sv = (k < 4) ? sbox[k * hw + idx] : sang[idx];
      float d = fabsf(sv - tgt[k]);
      sb += (d < 1.f) ? 0.5f * d * d : d - 0.5f;
    }
    v1 = sb * lw;
    v2 = 0.f;
    if (lp) {
      float p = siou;
      if (p < 1e-12f) p = 1e-12f;
      float pu = 1.f - 1e-12f;
      if (p > pu) p = pu;
      float ti = g_sig_tiou[n];
      v2 = -(ti * logf(p) + (1.f - ti) * log1pf(-p));
    }
    v3 = pm ? ctmax : 0.f;   // cls_avg
    v4 = lw;                 // loc_avg
    v5 = lp ? 1.f : 0.f;     // iou_avg
  }
  red[0][tid] = v0; red[1][tid] = v1; red[2][tid] = v2;
  red[3][tid] = v3; red[4][tid] = v4; red[5][tid] = v5;
  __syncthreads();
  for (int st = 128; st > 0; st >>= 1) {
    if (tid < st)
#pragma unroll
      for (int k = 0; k < 6; k++) red[k][tid] += red[k][tid + st];
    __syncthreads();
  }
  if (tid == 0)
#pragma unroll
    for (int k = 0; k < 6; k++) g_partials[t * 6 + k] = red[k][0];

  // last-done block performs the final reduce and writes the output
  __threadfence();
  if (tid == 0) {
    unsigned long long dv = atomicAdd(&g_done_loss, 1ull);
    s_last = ((dv % (unsigned long long)TILES) == (unsigned long long)(TILES - 1)) ? 1 : 0;
  }
  __syncthreads();
  if (s_last) {
    __threadfence();
    float a[6] = {0,0,0,0,0,0};
    for (int i = tid; i < TILES; i += 256)
#pragma unroll
      for (int k = 0; k < 6; k++) a[k] += g_partials[i * 6 + k];
    __syncthreads();
#pragma unroll
    for (int k = 0; k < 6; k++) red[k][tid] = a[k];
    __syncthreads();
    for (int st = 128; st > 0; st >>= 1) {
      if (tid < st)
#pragma unroll
        for (int k = 0; k < 6; k++) red[k][tid] += red[k][tid + st];
      __syncthreads();
    }
    if (tid == 0) {
      out[0] = red[0][0] / fmaxf(red[3][0], 1e-8f);
      out[1] = red[1][0] / fmaxf(red[4][0], 1e-8f);
      out[2] = red[2][0] / fmaxf(red[5][0], 1.f);
    }
  }
}

extern "C" void kernel_launch(void* const* d_in, const int* in_sizes, int n_in,
                              void* d_out, int out_size, void* d_ws, size_t ws_size,
                              hipStream_t stream) {
  (void)in_sizes; (void)n_in; (void)out_size; (void)d_ws; (void)ws_size;
  InPtrs P;
  for (int i = 0; i < 40; i++) P.p[i] = (const float*)d_in[i];
  k_prep<<<TILES, 256, 0, stream>>>(P);
  k_maskcompact<<<TILES, 256, 0, stream>>>();
  k_iou<<<KHN, 256, 0, stream>>>(P);
  k_loss<<<TILES, 256, 0, stream>>>(P, (float*)d_out);
}

// Round 10
// 148.197 us; speedup vs baseline: 6295.4849x; 1.0454x over previous
//
#include <hip/hip_runtime.h>
#include <math.h>

#define NPTS 87296
#define NCLS 16
#define KPOS 256
#define KHN  2048
#define TILES 341           // NPTS / 256 exactly
#define CAP  4096           // compacted-candidate capacity (slow path beyond)
#define PI_F   3.14159265358979323846f
#define HPI_F  1.57079632679489661923f

struct InPtrs { const float* p[40]; };
// input index = pre*20 + lvl*4 + {cls:0, box:1, ang:2, ctr:3}; pre: t=0, s=1

// ---------------- persistent device scratch (rewritten every call) ----------------
__device__ float g_max_vals[NPTS];
__device__ float g_sig_tiou[NPTS];
__device__ float g_sig_cls_max[NPTS];
__device__ int   g_class_ind[NPTS];
__device__ int   g_pos_mask[NPTS];
__device__ int   g_hn_mask[NPTS];
__device__ int   g_hnflag[NPTS];
__device__ float g_loc_targets[NPTS * 5]; // only hn slots are written/read
__device__ float g_bsum[TILES];
__device__ float g_bsumsq[TILES];
__device__ int   g_bcnt[TILES];
__device__ int   g_bpos[TILES];
__device__ int   g_bhn[TILES];
__device__ int   g_pos_off[TILES];
__device__ int   g_hn_off[TILES];
__device__ float g_thresh;
__device__ int   g_tp, g_thn, g_slow;
__device__ int   g_pos_cand[CAP];
__device__ int   g_hn_cand[CAP];
__device__ int   g_pidx[KPOS];
__device__ int   g_pvalid[KPOS];
__device__ float g_pv[KPOS];
__device__ int   g_hidx[KHN];
__device__ int   g_hvalid[KHN];
// coalesced decoded-candidate arrays (fast path)
__device__ float g_pos_bbox[KPOS * 5];
__device__ float g_pos_cor[KPOS * 8];
__device__ float g_pos_area[KPOS];
__device__ float g_pos_scale[KPOS];
__device__ int   g_pos_class[KPOS];
__device__ float g_hn_px[KHN];
__device__ float g_hn_py[KHN];
__device__ float g_hn_cor[KHN * 8];
__device__ float g_hn_area[KHN];
__device__ float g_hn_scale[KHN];
__device__ int   g_hn_class[KHN];
__device__ float g_partials[TILES * 6];
// monotonic last-done epoch counters (never reset; survive graph replays)
__device__ unsigned long long g_done_prep = 0ull;
__device__ unsigned long long g_done_mask = 0ull;
__device__ unsigned long long g_done_cmp  = 0ull;
__device__ unsigned long long g_done_loss = 0ull;

// ---------------- helpers ----------------
__device__ __forceinline__ float sigmoidf(float x) {
  if (x >= 0.f) return 1.f / (1.f + expf(-x));
  float e = expf(x);
  return e / (1.f + e);
}
__device__ __forceinline__ float crs(float ax, float ay, float bx, float by) {
  return ax * by - ay * bx;
}
__device__ __forceinline__ float mod_pos(float x, float y) {
  float r = fmodf(x, y);
  if (r < 0.f) r += y;
  return r;
}
// monotonic pseudo-angle: strictly increasing map of atan2(dy,dx) -> (-2,2]
__device__ __forceinline__ float pseudo_ang(float dx, float dy) {
  float den = fabsf(dx) + fabsf(dy);
  if (den == 0.f) return 0.f;         // matches atan2(0,0)=0 tie class
  return copysignf(1.f - dx / den, dy);
}
__device__ __forceinline__ void point_info(int n, int& lvl, int& idx, int& hw,
                                           float& px, float& py) {
  int off, wsh; float stride;
  if (n < 65536)      { lvl = 0; off = 0;     wsh = 8; stride = 8.f;   hw = 65536; }
  else if (n < 81920) { lvl = 1; off = 65536; wsh = 7; stride = 16.f;  hw = 16384; }
  else if (n < 86016) { lvl = 2; off = 81920; wsh = 6; stride = 32.f;  hw = 4096; }
  else if (n < 87040) { lvl = 3; off = 86016; wsh = 5; stride = 64.f;  hw = 1024; }
  else                { lvl = 4; off = 87040; wsh = 4; stride = 128.f; hw = 256; }
  idx = n - off;
  int y = idx >> wsh, x = idx & ((1 << wsh) - 1);
  px = ((float)x + 0.5f) * stride;
  py = ((float)y + 0.5f) * stride;
}

// ---------------- radix select paths (rare; 256-thread block variants) ----------------
#define MASK_ALL 0
#define MASK_POS 1
#define MASK_HN  2
__device__ __forceinline__ int sel_mask(int mode, int n) {
  return mode == MASK_ALL ? 1 : (mode == MASK_POS ? g_pos_mask[n] : g_hn_mask[n]);
}

__device__ void radix_select_mask(int mode, int K, int* out_idx, int* out_valid, float* out_val,
                                  int* hist, int* scan_a, int* scan_b, int* sh) {
  int tid = threadIdx.x;
  int c = 0;
  for (int n = tid; n < NPTS; n += 256) if (sel_mask(mode, n)) c++;
  scan_a[tid] = c; __syncthreads();
  for (int st = 128; st > 0; st >>= 1) {
    if (tid < st) scan_a[tid] += scan_a[tid + st];
    __syncthreads();
  }
  int total = scan_a[0];
  __syncthreads();

  unsigned kth = 0u;
  if (total > K) {
    unsigned prefix = 0; int rem = K;
    for (int pass = 0; pass < 4; pass++) {
      int shift = 24 - 8 * pass;
      hist[tid] = 0;
      __syncthreads();
      for (int n = tid; n < NPTS; n += 256) {
        if (sel_mask(mode, n)) {
          unsigned k = __float_as_uint(g_max_vals[n]);
          if (pass == 0 || ((k >> (shift + 8)) == prefix))
            atomicAdd(&hist[(k >> shift) & 255], 1);
        }
      }
      __syncthreads();
      if (tid == 0) {
        int cum = 0, b = 255;
        for (; b > 0; b--) {
          if (cum + hist[b] >= rem) break;
          cum += hist[b];
        }
        sh[0] = (int)((prefix << 8) | (unsigned)b);
        sh[1] = rem - cum;
      }
      __syncthreads();
      prefix = (unsigned)sh[0]; rem = sh[1];
      __syncthreads();
    }
    kth = prefix;
  }

  const int chunk = (NPTS + 255) / 256;
  int start = tid * chunk; if (start > NPTS) start = NPTS;
  int end = start + chunk; if (end > NPTS) end = NPTS;
  int cgt = 0, ceq = 0;
  for (int n = start; n < end; n++) {
    if (sel_mask(mode, n)) {
      unsigned k = __float_as_uint(g_max_vals[n]);
      if (k > kth) cgt++;
      else if (k == kth) ceq++;
    }
  }
  scan_a[tid] = cgt; scan_b[tid] = ceq; __syncthreads();
  if (tid == 0) {
    int ag = 0, ae = 0;
    for (int i = 0; i < 256; i++) {
      int tg = scan_a[i], te = scan_b[i];
      scan_a[i] = ag; scan_b[i] = ae;
      ag += tg; ae += te;
    }
    sh[0] = ag; sh[1] = ae;
  }
  __syncthreads();
  int cnt_gt = sh[0], cnt_eq = sh[1];
  int og = scan_a[tid], oe = cnt_gt + scan_b[tid];
  for (int n = start; n < end; n++) {
    if (sel_mask(mode, n)) {
      unsigned k = __float_as_uint(g_max_vals[n]);
      if (k > kth) {
        out_idx[og] = n; out_valid[og] = 1;
        if (out_val) out_val[og] = g_max_vals[n];
        og++;
      } else if (k == kth) {
        if (oe < K) {
          out_idx[oe] = n; out_valid[oe] = 1;
          if (out_val) out_val[oe] = g_max_vals[n];
        }
        oe++;
      }
    }
  }
  int kmc = K - cnt_gt;
  int used = cnt_gt + (cnt_eq < kmc ? cnt_eq : kmc);
  __syncthreads();
  for (int i = used + tid; i < K; i += 256) {
    out_idx[i] = 0; out_valid[i] = 0;
    if (out_val) out_val[i] = -1.f;
  }
  __syncthreads();
}

__device__ void radix_select_list(const int* list, int count, int K,
                                  int* out_idx, int* out_valid, float* out_val,
                                  int* hist, int* scan_a, int* scan_b, int* sh) {
  // requires count > K
  int tid = threadIdx.x;
  unsigned prefix = 0; int rem = K;
  for (int pass = 0; pass < 4; pass++) {
    int shift = 24 - 8 * pass;
    hist[tid] = 0;
    __syncthreads();
    for (int i = tid; i < count; i += 256) {
      unsigned k = __float_as_uint(g_max_vals[list[i]]);
      if (pass == 0 || ((k >> (shift + 8)) == prefix))
        atomicAdd(&hist[(k >> shift) & 255], 1);
    }
    __syncthreads();
    if (tid == 0) {
      int cum = 0, b = 255;
      for (; b > 0; b--) {
        if (cum + hist[b] >= rem) break;
        cum += hist[b];
      }
      sh[0] = (int)((prefix << 8) | (unsigned)b);
      sh[1] = rem - cum;
    }
    __syncthreads();
    prefix = (unsigned)sh[0]; rem = sh[1];
    __syncthreads();
  }
  unsigned kth = prefix;
  int chunk = (count + 255) / 256;
  int start = tid * chunk; if (start > count) start = count;
  int end = start + chunk; if (end > count) end = count;
  int cgt = 0, ceq = 0;
  for (int i = start; i < end; i++) {
    unsigned k = __float_as_uint(g_max_vals[list[i]]);
    if (k > kth) cgt++;
    else if (k == kth) ceq++;
  }
  scan_a[tid] = cgt; scan_b[tid] = ceq; __syncthreads();
  if (tid == 0) {
    int ag = 0, ae = 0;
    for (int i = 0; i < 256; i++) {
      int tg = scan_a[i], te = scan_b[i];
      scan_a[i] = ag; scan_b[i] = ae;
      ag += tg; ae += te;
    }
    sh[0] = ag;
  }
  __syncthreads();
  int cnt_gt = sh[0];
  int og = scan_a[tid], oe = cnt_gt + scan_b[tid];
  for (int i = start; i < end; i++) {
    int n = list[i];
    unsigned k = __float_as_uint(g_max_vals[n]);
    if (k > kth) {
      out_idx[og] = n; out_valid[og] = 1;
      if (out_val) out_val[og] = g_max_vals[n];
      og++;
    } else if (k == kth) {
      if (oe < K) {
        out_idx[oe] = n; out_valid[oe] = 1;
        if (out_val) out_val[oe] = g_max_vals[n];
      }
      oe++;
    }
  }
  __syncthreads();
}

__device__ void slow_select_block(int tp, int thn, int fallback,
                                  int* hist, int* si0, int* si1, int* sh_i) {
  int tid = threadIdx.x;
  if (!fallback && tp <= KPOS) {
    for (int i = tid; i < KPOS; i += 256) {
      if (i < tp) {
        int m = g_pos_cand[i];
        g_pidx[i] = m; g_pvalid[i] = 1; g_pv[i] = g_max_vals[m];
      } else { g_pidx[i] = 0; g_pvalid[i] = 0; g_pv[i] = -1.f; }
    }
    __syncthreads();
  } else if (!fallback && tp <= CAP) {
    radix_select_list(g_pos_cand, tp, KPOS, g_pidx, g_pvalid, g_pv, hist, si0, si1, sh_i);
  } else if (!fallback) {
    radix_select_mask(MASK_POS, KPOS, g_pidx, g_pvalid, g_pv, hist, si0, si1, sh_i);
  } else {
    radix_select_mask(MASK_ALL, 10, g_pidx, g_pvalid, g_pv, hist, si0, si1, sh_i);
    for (int i = tid; i < 10; i += 256)
      if (g_pvalid[i]) g_pos_mask[g_pidx[i]] = 1;
    for (int i = 10 + tid; i < KPOS; i += 256) {
      g_pidx[i] = 0; g_pvalid[i] = 0; g_pv[i] = -1.f;
    }
    __syncthreads();
  }
  if (thn <= KHN) {
    for (int i = tid; i < KHN; i += 256) {
      if (i < thn) { g_hidx[i] = g_hn_cand[i]; g_hvalid[i] = 1; }
      else { g_hidx[i] = 0; g_hvalid[i] = 0; }
    }
  } else if (thn <= CAP) {
    radix_select_list(g_hn_cand, thn, KHN, g_hidx, g_hvalid, (float*)0, hist, si0, si1, sh_i);
  } else {
    radix_select_mask(MASK_HN, KHN, g_hidx, g_hvalid, (float*)0, hist, si0, si1, sh_i);
  }
}

// ---------------- decode helper ----------------
__device__ void decode_box(int n, const InPtrs& P, float* bb, float* cor,
                           float& area, float& scale, int& cls_out,
                           float* opx, float* opy) {
  int lvl, idx, hw; float px, py;
  point_info(n, lvl, idx, hw, px, py);
  const float* box = P.p[lvl * 4 + 1];
  const float* ang = P.p[lvl * 4 + 2];
  float l = box[idx], t = box[hw + idx], r = box[2 * hw + idx], b = box[3 * hw + idx];
  float a = ang[idx];
  float ca = cosf(a), sa = sinf(a);
  float w = l + r, h = t + b;
  float oxl = (r - l) * 0.5f, oyl = (b - t) * 0.5f;
  float ox = ca * oxl - sa * oyl;
  float oy = sa * oxl + ca * oyl;
  float an = mod_pos(a + HPI_F, PI_F) - HPI_F;
  float cx = px + ox, cy = py + oy;
  bb[0] = cx; bb[1] = cy; bb[2] = w; bb[3] = h; bb[4] = an;
  float c2 = cosf(an), s2 = sinf(an);
  const float dxs[4] = {-0.5f, 0.5f, 0.5f, -0.5f};
  const float dys[4] = {-0.5f, -0.5f, 0.5f, 0.5f};
#pragma unroll
  for (int k = 0; k < 4; k++) {
    float dx = dxs[k] * w, dy = dys[k] * h;
    cor[2 * k]     = cx + dx * c2 - dy * s2;
    cor[2 * k + 1] = cy + dx * s2 + dy * c2;
  }
  area = fabsf(w * h);
  scale = (float)lvl;
  cls_out = g_class_ind[n];
  if (opx) { *opx = px; *opy = py; }
}

// ---------------- convex quad intersection — fully register-resident ----------------
#define BPASS(KK, JJ)                                                      \
  _Pragma("unroll")                                                        \
  for (int i = 0; i < 32; i++) {                                           \
    int l = i ^ (JJ);                                                      \
    if (l > i) {                                                           \
      bool up = ((i & (KK)) == 0);                                         \
      float aa = sa_[i], ab = sa_[l];                                      \
      bool sw = up ? (aa > ab) : (aa < ab);                                \
      sa_[i] = sw ? ab : aa; sa_[l] = sw ? aa : ab;                        \
      float xi = sx_[i], xl = sx_[l];                                      \
      sx_[i] = sw ? xl : xi; sx_[l] = sw ? xi : xl;                        \
      float yi = sy_[i], yl = sy_[l];                                      \
      sy_[i] = sw ? yl : yi; sy_[l] = sw ? yi : yl;                        \
    }                                                                      \
  }

__device__ float inter_area(const float* __restrict__ A, const float* __restrict__ B) {
  float ax[4], ay[4], bx[4], by[4];
#pragma unroll
  for (int i = 0; i < 4; i++) {
    ax[i] = A[2 * i]; ay[i] = A[2 * i + 1];
    bx[i] = B[2 * i]; by[i] = B[2 * i + 1];
  }
  float dax[4], day[4], dbx[4], dby[4];
#pragma unroll
  for (int i = 0; i < 4; i++) {
    int i1 = (i + 1) & 3;
    dax[i] = ax[i1] - ax[i]; day[i] = ay[i1] - ay[i];
    dbx[i] = bx[i1] - bx[i]; dby[i] = by[i1] - by[i];
  }
  float px[24], py[24]; bool val[24];
#pragma unroll
  for (int i = 0; i < 4; i++) {
#pragma unroll
    for (int j = 0; j < 4; j++) {
      float dx = bx[j] - ax[i], dy = by[j] - ay[i];
      float den = crs(dax[i], day[i], dbx[j], dby[j]);
      float ad = fabsf(den);
      float ds = (ad < 1e-10f) ? 1.0f : den;
      float t = crs(dx, dy, dbx[j], dby[j]) / ds;
      float u = crs(dx, dy, dax[i], day[i]) / ds;
      bool ok = (ad > 1e-10f) & (t >= 0.f) & (t <= 1.f) & (u >= 0.f) & (u <= 1.f);
      int k = i * 4 + j;
      px[k] = ax[i] + t * dax[i];
      py[k] = ay[i] + t * day[i];
      val[k] = ok;
    }
  }
#pragma unroll
  for (int i = 0; i < 4; i++) {   // corners of A inside B
    bool ge = true, le = true;
#pragma unroll
    for (int j = 0; j < 4; j++) {
      float s = crs(dbx[j], dby[j], ax[i] - bx[j], ay[i] - by[j]);
      ge = ge && (s >= -1e-9f);
      le = le && (s <= 1e-9f);
    }
    val[16 + i] = ge || le; px[16 + i] = ax[i]; py[16 + i] = ay[i];
  }
#pragma unroll
  for (int j = 0; j < 4; j++) {   // corners of B inside A
    bool ge = true, le = true;
#pragma unroll
    for (int i = 0; i < 4; i++) {
      float s = crs(dax[i], day[i], bx[j] - ax[i], by[j] - ay[i]);
      ge = ge && (s >= -1e-9f);
      le = le && (s <= 1e-9f);
    }
    val[20 + j] = ge || le; px[20 + j] = bx[j]; py[20 + j] = by[j];
  }
  int n = 0; float sx = 0.f, sy = 0.f;
#pragma unroll
  for (int k = 0; k < 24; k++) if (val[k]) { n++; sx += px[k]; sy += py[k]; }
  float dn = (float)(n > 1 ? n : 1);
  float cx = sx / dn, cy = sy / dn;

  // 24 real slots (invalid collapse to centroid) + 8 +INF dummies; non-stable
  // network OK: angle ties only among identical centroid points (zero terms).
  float sa_[32], sx_[32], sy_[32];
#pragma unroll
  for (int k = 0; k < 24; k++) {
    float X = val[k] ? px[k] : cx;
    float Y = val[k] ? py[k] : cy;
    sx_[k] = X; sy_[k] = Y;
    sa_[k] = pseudo_ang(X - cx, Y - cy);
  }
#pragma unroll
  for (int k = 24; k < 32; k++) {
    sa_[k] = __int_as_float(0x7f800000);  // +inf
    sx_[k] = cx; sy_[k] = cy;
  }
  BPASS(2, 1)
  BPASS(4, 2)  BPASS(4, 1)
  BPASS(8, 4)  BPASS(8, 2)  BPASS(8, 1)
  BPASS(16, 8) BPASS(16, 4) BPASS(16, 2) BPASS(16, 1)
  BPASS(32, 16) BPASS(32, 8) BPASS(32, 4) BPASS(32, 2) BPASS(32, 1)

  float s2 = 0.f;
#pragma unroll
  for (int k = 0; k < 24; k++) {
    int k1 = (k + 1) % 24;
    s2 += crs(sx_[k] - cx, sy_[k] - cy, sx_[k1] - cx, sy_[k1] - cy);
  }
  float area = 0.5f * fabsf(s2);
  return (n >= 3) ? area : 0.f;
}

// ================= kernel 1: per-point stats + partials; last block -> threshold =================
__global__ __launch_bounds__(256) void k_prep(InPtrs P) {
  int tid = threadIdx.x;
  int t = blockIdx.x;
  int n = t * 256 + tid;
  __shared__ float r0[256], r1[256], r2[256];
  __shared__ int   si0[256];
  __shared__ int   s_last;

  int lvl, idx, hw; float px, py;
  point_info(n, lvl, idx, hw, px, py);
  const float* cls = P.p[lvl * 4 + 0];
  const float* ctr = P.p[lvl * 4 + 3];
  float stiou = sigmoidf(ctr[idx]);
  float mv = -1.f, scm = 0.f; int ci = 0;
  for (int c = 0; c < NCLS; c++) {
    float sc = sigmoidf(cls[c * hw + idx]);
    if (sc > scm) scm = sc;
    float j = sc * stiou;
    if (j > mv) { mv = j; ci = c; }
  }
  g_max_vals[n] = mv;
  g_class_ind[n] = ci;
  g_sig_tiou[n] = stiou;
  g_sig_cls_max[n] = scm;
  g_hnflag[n] = 0;
  float isc = (mv >= 0.1f) ? 1.f : 0.f;
  r0[tid] = isc; r1[tid] = isc * mv; r2[tid] = isc * mv * mv;
  __syncthreads();
  for (int st = 128; st > 0; st >>= 1) {
    if (tid < st) { r0[tid] += r0[tid + st]; r1[tid] += r1[tid + st]; r2[tid] += r2[tid + st]; }
    __syncthreads();
  }
  if (tid == 0) {
    g_bcnt[t] = (int)r0[0];
    g_bsum[t] = r1[0];
    g_bsumsq[t] = r2[0];
  }
  __threadfence();
  if (tid == 0) {
    unsigned long long v = atomicAdd(&g_done_prep, 1ull);
    s_last = ((v % (unsigned long long)TILES) == (unsigned long long)(TILES - 1)) ? 1 : 0;
  }
  __syncthreads();
  if (s_last) {
    __threadfence();
    int c = 0; float s = 0.f, q = 0.f;
    for (int i = tid; i < TILES; i += 256) { c += g_bcnt[i]; s += g_bsum[i]; q += g_bsumsq[i]; }
    __syncthreads();
    si0[tid] = c; r0[tid] = s; r1[tid] = q; __syncthreads();
    for (int st = 128; st > 0; st >>= 1) {
      if (tid < st) { si0[tid] += si0[tid + st]; r0[tid] += r0[tid + st]; r1[tid] += r1[tid + st]; }
      __syncthreads();
    }
    if (tid == 0) {
      int nc = si0[0]; float sum = r0[0], sumsq = r1[0];
      float mean = sum / (float)(nc > 1 ? nc : 1);
      float E = sumsq - 2.f * mean * sum + (float)nc * mean * mean;
      if (E < 0.f) E = 0.f;
      float var = E / (float)((nc - 1) > 1 ? (nc - 1) : 1);
      float th = fminf(mean + sqrtf(var), 0.4f);
      if (nc == 0) th = __int_as_float(0x7f800000);  // +inf
      g_thresh = th;
    }
  }
}

// ========== kernel 2: masks + per-tile counts; last block -> LDS scan of 341 counts ==========
__global__ __launch_bounds__(256) void k_mask() {
  int tid = threadIdx.x;
  int t = blockIdx.x;
  int n = t * 256 + tid;
  __shared__ int si0[256], si1[256];
  __shared__ int sp[512], sh_[512];
  __shared__ int s_last;

  float th = g_thresh;
  float v = g_max_vals[n];
  int pm = (v >= th) ? 1 : 0;
  int hm = (v >= 0.1f && v < th) ? 1 : 0;
  g_pos_mask[n] = pm; g_hn_mask[n] = hm;
  si0[tid] = pm; si1[tid] = hm; __syncthreads();
  for (int st = 128; st > 0; st >>= 1) {
    if (tid < st) { si0[tid] += si0[tid + st]; si1[tid] += si1[tid + st]; }
    __syncthreads();
  }
  if (tid == 0) { g_bpos[t] = si0[0]; g_bhn[t] = si1[0]; }

  __threadfence();
  if (tid == 0) {
    unsigned long long dv = atomicAdd(&g_done_mask, 1ull);
    s_last = ((dv % (unsigned long long)TILES) == (unsigned long long)(TILES - 1)) ? 1 : 0;
  }
  __syncthreads();
  if (s_last) {
    __threadfence();
    // Hillis-Steele inclusive scan over 512 padded slots (2 per thread)
    int vp0 = (tid < TILES) ? g_bpos[tid] : 0;
    int vp1 = (tid + 256 < TILES) ? g_bpos[tid + 256] : 0;
    int vh0 = (tid < TILES) ? g_bhn[tid] : 0;
    int vh1 = (tid + 256 < TILES) ? g_bhn[tid + 256] : 0;
    sp[tid] = vp0; sp[tid + 256] = vp1;
    sh_[tid] = vh0; sh_[tid + 256] = vh1;
    __syncthreads();
    for (int off = 1; off < 512; off <<= 1) {
      int a0 = (tid >= off) ? sp[tid - off] : 0;
      int a1 = (tid + 256 >= off) ? sp[tid + 256 - off] : 0;
      int b0 = (tid >= off) ? sh_[tid - off] : 0;
      int b1 = (tid + 256 >= off) ? sh_[tid + 256 - off] : 0;
      __syncthreads();
      sp[tid] += a0; sp[tid + 256] += a1;
      sh_[tid] += b0; sh_[tid + 256] += b1;
      __syncthreads();
    }
    if (tid < TILES) g_pos_off[tid] = sp[tid] - vp0;
    if (tid + 256 < TILES) g_pos_off[tid + 256] = sp[tid + 256] - vp1;
    if (tid < TILES) g_hn_off[tid] = sh_[tid] - vh0;
    if (tid + 256 < TILES) g_hn_off[tid + 256] = sh_[tid + 256] - vh1;
    if (tid == 0) {
      int tp = sp[TILES - 1], thn = sh_[TILES - 1];
      g_tp = tp; g_thn = thn;
      g_slow = (tp == 0 || tp > KPOS || thn > KHN) ? 1 : 0;
    }
  }
}

// ========== kernel 3: compaction + inline decode of own candidates; last block -> slow select ==========
__global__ __launch_bounds__(256) void k_compact(InPtrs P) {
  int tid = threadIdx.x;
  int t = blockIdx.x;
  int n = t * 256 + tid;
  __shared__ int si0[256], si1[256];
  __shared__ int hist[256];
  __shared__ int sh_i[2];
  __shared__ int s_last;

  int pm = g_pos_mask[n], hm = g_hn_mask[n];
  int poff = g_pos_off[t], hoff = g_hn_off[t];
  si0[tid] = pm; si1[tid] = hm; __syncthreads();
  for (int off = 1; off < 256; off <<= 1) {
    int ap = (tid >= off) ? si0[tid - off] : 0;
    int ah = (tid >= off) ? si1[tid - off] : 0;
    __syncthreads();
    si0[tid] += ap; si1[tid] += ah;
    __syncthreads();
  }
  if (pm) {
    int o = poff + si0[tid] - pm;
    if (o < CAP) g_pos_cand[o] = n;
    if (o < KPOS) {   // fast-path decode into coalesced arrays
      float bb[5], cor[8], ar, sc; int cl;
      decode_box(n, P, bb, cor, ar, sc, cl, (float*)0, (float*)0);
#pragma unroll
      for (int k = 0; k < 5; k++) g_pos_bbox[o * 5 + k] = bb[k];
#pragma unroll
      for (int k = 0; k < 8; k++) g_pos_cor[o * 8 + k] = cor[k];
      g_pos_area[o] = ar; g_pos_scale[o] = sc; g_pos_class[o] = cl;
      g_pv[o] = g_max_vals[n];
    }
  }
  if (hm) {
    int o = hoff + si1[tid] - hm;
    if (o < CAP) g_hn_cand[o] = n;
    if (o < KHN) {
      float bb[5], cor[8], ar, sc, px, py; int cl;
      decode_box(n, P, bb, cor, ar, sc, cl, &px, &py);
#pragma unroll
      for (int k = 0; k < 8; k++) g_hn_cor[o * 8 + k] = cor[k];
      g_hn_area[o] = ar; g_hn_scale[o] = sc; g_hn_class[o] = cl;
      g_hn_px[o] = px; g_hn_py[o] = py;
    }
  }

  __threadfence();
  if (tid == 0) {
    unsigned long long dv = atomicAdd(&g_done_cmp, 1ull);
    s_last = ((dv % (unsigned long long)TILES) == (unsigned long long)(TILES - 1)) ? 1 : 0;
  }
  __syncthreads();
  if (s_last && g_slow) {
    __threadfence();
    int tp = g_tp, thn = g_thn;
    int fallback = (tp == 0) ? 1 : 0;
    slow_select_block(tp, thn, fallback, hist, si0, si1, sh_i);
  }
}

// ============ kernel 4: IoU + aggregation + scatter ============
__global__ __launch_bounds__(256) void k_iou(InPtrs P) {
  const int h = blockIdx.x;
  const int j = threadIdx.x;
  const int slow = g_slow;
  const int tp = g_tp, thn = g_thn;

  const int hv = slow ? g_hvalid[h] : ((h < thn) ? 1 : 0);
  if (!hv) return;   // block-uniform

  int nh; float hcor[8], har, hsc, hpx, hpy; int hcl;
  if (slow) {
    nh = g_hidx[h];
    float hbb[5];
    decode_box(nh, P, hbb, hcor, har, hsc, hcl, &hpx, &hpy);
  } else {
    nh = g_hn_cand[h];
#pragma unroll
    for (int k = 0; k < 8; k++) hcor[k] = g_hn_cor[h * 8 + k];
    har = g_hn_area[h]; hsc = g_hn_scale[h]; hcl = g_hn_class[h];
    hpx = g_hn_px[h]; hpy = g_hn_py[h];
  }

  float wsum = 0.f, wb[5] = {0,0,0,0,0}, anyv = 0.f;
  const int pvld = slow ? g_pvalid[j] : ((j < tp) ? 1 : 0);
  if (pvld) {
    float pbb[5], pcor[8], par, psc, pv; int pcl;
    if (slow) {
      int m = g_pidx[j];
      pv = g_pv[j];
      decode_box(m, P, pbb, pcor, par, psc, pcl, (float*)0, (float*)0);
    } else {
#pragma unroll
      for (int k = 0; k < 5; k++) pbb[k] = g_pos_bbox[j * 5 + k];
#pragma unroll
      for (int k = 0; k < 8; k++) pcor[k] = g_pos_cor[j * 8 + k];
      par = g_pos_area[j]; psc = g_pos_scale[j]; pcl = g_pos_class[j];
      pv = g_pv[j];
    }
    bool valid = (pcl == hcl) && (fabsf(psc - hsc) <= 1.0f);
    if (valid) {
      float ca = cosf(pbb[4]), sa = sinf(pbb[4]);
      float dx = hpx - pbb[0], dy = hpy - pbb[1];
      float ox = ca * dx + sa * dy, oy = -sa * dx + ca * dy;
      float mm = fminf(fminf(pbb[2] * 0.5f + ox, pbb[2] * 0.5f - ox),
                       fminf(pbb[3] * 0.5f + oy, pbb[3] * 0.5f - oy));
      valid = (mm > 0.f);
    }
    if (valid) {
      float inter = inter_area(hcor, pcor);
      float iou = inter / (har + par - inter + 1e-8f);
      valid = (iou >= 0.6f);
    }
    if (valid) {
      anyv = 1.f; wsum = pv;
#pragma unroll
      for (int k = 0; k < 5; k++) wb[k] = pv * pbb[k];
    }
  }
  __shared__ float red[7][256];
  red[0][j] = wsum;
#pragma unroll
  for (int k = 0; k < 5; k++) red[1 + k][j] = wb[k];
  red[6][j] = anyv;
  __syncthreads();
  for (int st = 128; st > 0; st >>= 1) {
    if (j < st)
#pragma unroll
      for (int k = 0; k < 7; k++) red[k][j] += red[k][j + st];
    __syncthreads();
  }
  if (j == 0 && red[6][0] > 0.f) {
    float inv = 1.f / fmaxf(red[0][0], 1e-8f);
    float bb[5];
#pragma unroll
    for (int k = 0; k < 5; k++) bb[k] = red[1 + k][0] * inv;
    float ca = cosf(bb[4]), sa = sinf(bb[4]);
    float dx = hpx - bb[0], dy = hpy - bb[1];
    float ox = ca * dx + sa * dy, oy = -sa * dx + ca * dy;
    g_loc_targets[nh * 5 + 0] = bb[2] * 0.5f + ox;
    g_loc_targets[nh * 5 + 1] = bb[3] * 0.5f + oy;
    g_loc_targets[nh * 5 + 2] = bb[2] * 0.5f - ox;
    g_loc_targets[nh * 5 + 3] = bb[3] * 0.5f - oy;
    g_loc_targets[nh * 5 + 4] = bb[4];
    g_hnflag[nh] = 1;
  }
}

// ============ kernel 5: per-point losses -> partials; last block -> final + output ============
__global__ __launch_bounds__(256) void k_loss(InPtrs P, float* out) {
  int tid = threadIdx.x;
  int t = blockIdx.x;
  int n = t * 256 + tid;
  __shared__ float red[6][256];
  __shared__ int s_last;
  float v0, v1, v2, v3, v4, v5;
  {
    int lvl, idx, hw; float px, py;
    point_info(n, lvl, idx, hw, px, py);
    int pm = g_pos_mask[n], hm = g_hn_mask[n], hf = g_hnflag[n];
    int sel = pm | hm;
    bool lp = (pm | hf) != 0;
    float ctmax = sel ? g_sig_cls_max[n] : 0.f;
    const float* tcls = P.p[lvl * 4 + 0];
    const float* tbox = P.p[lvl * 4 + 1];
    const float* tang = P.p[lvl * 4 + 2];
    const float* scls = P.p[20 + lvl * 4 + 0];
    const float* sbox = P.p[20 + lvl * 4 + 1];
    const float* sang = P.p[20 + lvl * 4 + 2];
    const float* sctr = P.p[20 + lvl * 4 + 3];
    float siou = sigmoidf(sctr[idx]);
    float scl = 0.f;
    for (int c = 0; c < NCLS; c++) {
      float jc = sigmoidf(scls[c * hw + idx]) * siou;
      float ct = sel ? sigmoidf(tcls[c * hw + idx]) : 0.f;
      float p = jc;
      if (p < 1e-12f) p = 1e-12f;
      float pu = 1.f - 1e-12f;
      if (p > pu) p = pu;
      float bce = -(ct * logf(p) + (1.f - ct) * log1pf(-p));
      float d = fabsf(jc - ct);
      scl += bce * d * d;
    }
    v0 = scl;
    float lw = lp ? ctmax : 0.f;
    float tgt[5];
    if (hf) {
#pragma unroll
      for (int k = 0; k < 5; k++) tgt[k] = g_loc_targets[n * 5 + k];
    } else if (pm) {
      tgt[0] = tbox[idx]; tgt[1] = tbox[hw + idx];
      tgt[2] = tbox[2 * hw + idx]; tgt[3] = tbox[3 * hw + idx];
      tgt[4] = tang[idx];
    } else {
#pragma unroll
      for (int k = 0; k < 5; k++) tgt[k] = 0.f;
    }
    float sb = 0.f;
#pragma unroll
    for (int k = 0; k < 5; k++) {
      float sv = (k < 4) ? sbox[k * hw + idx] : sang[idx];
      float d = fabsf(sv - tgt[k]);
      sb += (d < 1.f) ? 0.5f * d * d : d - 0.5f;
    }
    v1 = sb * lw;
    v2 = 0.f;
    if (lp) {
      float p = siou;
      if (p < 1e-12f) p = 1e-12f;
      float pu = 1.f - 1e-12f;
      if (p > pu) p = pu;
      float ti = g_sig_tiou[n];
      v2 = -(ti * logf(p) + (1.f - ti) * log1pf(-p));
    }
    v3 = pm ? ctmax : 0.f;   // cls_avg
    v4 = lw;                 // loc_avg
    v5 = lp ? 1.f : 0.f;     // iou_avg
  }
  red[0][tid] = v0; red[1][tid] = v1; red[2][tid] = v2;
  red[3][tid] = v3; red[4][tid] = v4; red[5][tid] = v5;
  __syncthreads();
  for (int st = 128; st > 0; st >>= 1) {
    if (tid < st)
#pragma unroll
      for (int k = 0; k < 6; k++) red[k][tid] += red[k][tid + st];
    __syncthreads();
  }
  if (tid == 0)
#pragma unroll
    for (int k = 0; k < 6; k++) g_partials[t * 6 + k] = red[k][0];

  __threadfence();
  if (tid == 0) {
    unsigned long long dv = atomicAdd(&g_done_loss, 1ull);
    s_last = ((dv % (unsigned long long)TILES) == (unsigned long long)(TILES - 1)) ? 1 : 0;
  }
  __syncthreads();
  if (s_last) {
    __threadfence();
    float a[6] = {0,0,0,0,0,0};
    for (int i = tid; i < TILES; i += 256)
#pragma unroll
      for (int k = 0; k < 6; k++) a[k] += g_partials[i * 6 + k];
    __syncthreads();
#pragma unroll
    for (int k = 0; k < 6; k++) red[k][tid] = a[k];
    __syncthreads();
    for (int st = 128; st > 0; st >>= 1) {
      if (tid < st)
#pragma unroll
        for (int k = 0; k < 6; k++) red[k][tid] += red[k][tid + st];
      __syncthreads();
    }
    if (tid == 0) {
      out[0] = red[0][0] / fmaxf(red[3][0], 1e-8f);
      out[1] = red[1][0] / fmaxf(red[4][0], 1e-8f);
      out[2] = red[2][0] / fmaxf(red[5][0], 1.f);
    }
  }
}

extern "C" void kernel_launch(void* const* d_in, const int* in_sizes, int n_in,
                              void* d_out, int out_size, void* d_ws, size_t ws_size,
                              hipStream_t stream) {
  (void)in_sizes; (void)n_in; (void)out_size; (void)d_ws; (void)ws_size;
  InPtrs P;
  for (int i = 0; i < 40; i++) P.p[i] = (const float*)d_in[i];
  k_prep<<<TILES, 256, 0, stream>>>(P);
  k_mask<<<TILES, 256, 0, stream>>>();
  k_compact<<<TILES, 256, 0, stream>>>(P);
  k_iou<<<KHN, 256, 0, stream>>>(P);
  k_loss<<<TILES, 256, 0, stream>>>(P, (float*)d_out);
}

// Round 11
// 54.571 us; speedup vs baseline: 17096.2999x; 2.7156x over previous
//
#include <hip/hip_runtime.h>
#include <math.h>

#define NPTS 87296
#define NCLS 16
#define KPOS 256
#define KHN  2048
#define TILES 341           // NPTS / 256 exactly
#define CAP  4096           // compacted-candidate capacity (slow path beyond)
#define PI_F   3.14159265358979323846f
#define HPI_F  1.57079632679489661923f

struct InPtrs { const float* p[40]; };
// input index = pre*20 + lvl*4 + {cls:0, box:1, ang:2, ctr:3}; pre: t=0, s=1

// ---------------- persistent device scratch (rewritten every call) ----------------
__device__ float g_max_vals[NPTS];
__device__ float g_sig_tiou[NPTS];
__device__ float g_sig_cls_max[NPTS];
__device__ int   g_class_ind[NPTS];
__device__ int   g_pos_mask[NPTS];
__device__ int   g_hn_mask[NPTS];
__device__ int   g_hnflag[NPTS];
__device__ float g_loc_targets[NPTS * 5]; // only hn slots are written/read
__device__ float g_bsum[TILES];
__device__ float g_bsumsq[TILES];
__device__ int   g_bcnt[TILES];
__device__ int   g_bpos[TILES];
__device__ int   g_bhn[TILES];
__device__ float g_thresh;
__device__ int   g_tp, g_thn, g_slow;
__device__ int   g_pos_cand[CAP];
__device__ int   g_hn_cand[CAP];
__device__ int   g_pidx[KPOS];
__device__ int   g_pvalid[KPOS];
__device__ float g_pv[KPOS];
__device__ int   g_hidx[KHN];
__device__ int   g_hvalid[KHN];
// coalesced decoded-candidate arrays
__device__ float g_pos_bbox[KPOS * 5];
__device__ float g_pos_cor[KPOS * 8];
__device__ float g_pos_area[KPOS];
__device__ float g_pos_scale[KPOS];
__device__ int   g_pos_class[KPOS];
__device__ float g_hn_px[KHN];
__device__ float g_hn_py[KHN];
__device__ float g_hn_cor[KHN * 8];
__device__ float g_hn_area[KHN];
__device__ float g_hn_scale[KHN];
__device__ int   g_hn_class[KHN];
__device__ float g_partials[TILES * 6];

// ---------------- helpers ----------------
__device__ __forceinline__ float sigmoidf(float x) {
  if (x >= 0.f) return 1.f / (1.f + expf(-x));
  float e = expf(x);
  return e / (1.f + e);
}
__device__ __forceinline__ float crs(float ax, float ay, float bx, float by) {
  return ax * by - ay * bx;
}
__device__ __forceinline__ float mod_pos(float x, float y) {
  float r = fmodf(x, y);
  if (r < 0.f) r += y;
  return r;
}
// monotonic pseudo-angle: strictly increasing map of atan2(dy,dx) -> (-2,2]
__device__ __forceinline__ float pseudo_ang(float dx, float dy) {
  float den = fabsf(dx) + fabsf(dy);
  if (den == 0.f) return 0.f;         // matches atan2(0,0)=0 tie class
  return copysignf(1.f - dx / den, dy);
}
__device__ __forceinline__ void point_info(int n, int& lvl, int& idx, int& hw,
                                           float& px, float& py) {
  int off, wsh; float stride;
  if (n < 65536)      { lvl = 0; off = 0;     wsh = 8; stride = 8.f;   hw = 65536; }
  else if (n < 81920) { lvl = 1; off = 65536; wsh = 7; stride = 16.f;  hw = 16384; }
  else if (n < 86016) { lvl = 2; off = 81920; wsh = 6; stride = 32.f;  hw = 4096; }
  else if (n < 87040) { lvl = 3; off = 86016; wsh = 5; stride = 64.f;  hw = 1024; }
  else                { lvl = 4; off = 87040; wsh = 4; stride = 128.f; hw = 256; }
  idx = n - off;
  int y = idx >> wsh, x = idx & ((1 << wsh) - 1);
  px = ((float)x + 0.5f) * stride;
  py = ((float)y + 0.5f) * stride;
}

// ---------------- radix select paths (rare; 256-thread block variants) ----------------
#define MASK_ALL 0
#define MASK_POS 1
#define MASK_HN  2
__device__ __forceinline__ int sel_mask(int mode, int n) {
  return mode == MASK_ALL ? 1 : (mode == MASK_POS ? g_pos_mask[n] : g_hn_mask[n]);
}

__device__ void radix_select_mask(int mode, int K, int* out_idx, int* out_valid, float* out_val,
                                  int* hist, int* scan_a, int* scan_b, int* sh) {
  int tid = threadIdx.x;
  int c = 0;
  for (int n = tid; n < NPTS; n += 256) if (sel_mask(mode, n)) c++;
  scan_a[tid] = c; __syncthreads();
  for (int st = 128; st > 0; st >>= 1) {
    if (tid < st) scan_a[tid] += scan_a[tid + st];
    __syncthreads();
  }
  int total = scan_a[0];
  __syncthreads();

  unsigned kth = 0u;
  if (total > K) {
    unsigned prefix = 0; int rem = K;
    for (int pass = 0; pass < 4; pass++) {
      int shift = 24 - 8 * pass;
      hist[tid] = 0;
      __syncthreads();
      for (int n = tid; n < NPTS; n += 256) {
        if (sel_mask(mode, n)) {
          unsigned k = __float_as_uint(g_max_vals[n]);
          if (pass == 0 || ((k >> (shift + 8)) == prefix))
            atomicAdd(&hist[(k >> shift) & 255], 1);
        }
      }
      __syncthreads();
      if (tid == 0) {
        int cum = 0, b = 255;
        for (; b > 0; b--) {
          if (cum + hist[b] >= rem) break;
          cum += hist[b];
        }
        sh[0] = (int)((prefix << 8) | (unsigned)b);
        sh[1] = rem - cum;
      }
      __syncthreads();
      prefix = (unsigned)sh[0]; rem = sh[1];
      __syncthreads();
    }
    kth = prefix;
  }

  const int chunk = (NPTS + 255) / 256;
  int start = tid * chunk; if (start > NPTS) start = NPTS;
  int end = start + chunk; if (end > NPTS) end = NPTS;
  int cgt = 0, ceq = 0;
  for (int n = start; n < end; n++) {
    if (sel_mask(mode, n)) {
      unsigned k = __float_as_uint(g_max_vals[n]);
      if (k > kth) cgt++;
      else if (k == kth) ceq++;
    }
  }
  scan_a[tid] = cgt; scan_b[tid] = ceq; __syncthreads();
  if (tid == 0) {
    int ag = 0, ae = 0;
    for (int i = 0; i < 256; i++) {
      int tg = scan_a[i], te = scan_b[i];
      scan_a[i] = ag; scan_b[i] = ae;
      ag += tg; ae += te;
    }
    sh[0] = ag; sh[1] = ae;
  }
  __syncthreads();
  int cnt_gt = sh[0], cnt_eq = sh[1];
  int og = scan_a[tid], oe = cnt_gt + scan_b[tid];
  for (int n = start; n < end; n++) {
    if (sel_mask(mode, n)) {
      unsigned k = __float_as_uint(g_max_vals[n]);
      if (k > kth) {
        out_idx[og] = n; out_valid[og] = 1;
        if (out_val) out_val[og] = g_max_vals[n];
        og++;
      } else if (k == kth) {
        if (oe < K) {
          out_idx[oe] = n; out_valid[oe] = 1;
          if (out_val) out_val[oe] = g_max_vals[n];
        }
        oe++;
      }
    }
  }
  int kmc = K - cnt_gt;
  int used = cnt_gt + (cnt_eq < kmc ? cnt_eq : kmc);
  __syncthreads();
  for (int i = used + tid; i < K; i += 256) {
    out_idx[i] = 0; out_valid[i] = 0;
    if (out_val) out_val[i] = -1.f;
  }
  __syncthreads();
}

__device__ void radix_select_list(const int* list, int count, int K,
                                  int* out_idx, int* out_valid, float* out_val,
                                  int* hist, int* scan_a, int* scan_b, int* sh) {
  // requires count > K
  int tid = threadIdx.x;
  unsigned prefix = 0; int rem = K;
  for (int pass = 0; pass < 4; pass++) {
    int shift = 24 - 8 * pass;
    hist[tid] = 0;
    __syncthreads();
    for (int i = tid; i < count; i += 256) {
      unsigned k = __float_as_uint(g_max_vals[list[i]]);
      if (pass == 0 || ((k >> (shift + 8)) == prefix))
        atomicAdd(&hist[(k >> shift) & 255], 1);
    }
    __syncthreads();
    if (tid == 0) {
      int cum = 0, b = 255;
      for (; b > 0; b--) {
        if (cum + hist[b] >= rem) break;
        cum += hist[b];
      }
      sh[0] = (int)((prefix << 8) | (unsigned)b);
      sh[1] = rem - cum;
    }
    __syncthreads();
    prefix = (unsigned)sh[0]; rem = sh[1];
    __syncthreads();
  }
  unsigned kth = prefix;
  int chunk = (count + 255) / 256;
  int start = tid * chunk; if (start > count) start = count;
  int end = start + chunk; if (end > count) end = count;
  int cgt = 0, ceq = 0;
  for (int i = start; i < end; i++) {
    unsigned k = __float_as_uint(g_max_vals[list[i]]);
    if (k > kth) cgt++;
    else if (k == kth) ceq++;
  }
  scan_a[tid] = cgt; scan_b[tid] = ceq; __syncthreads();
  if (tid == 0) {
    int ag = 0, ae = 0;
    for (int i = 0; i < 256; i++) {
      int tg = scan_a[i], te = scan_b[i];
      scan_a[i] = ag; scan_b[i] = ae;
      ag += tg; ae += te;
    }
    sh[0] = ag;
  }
  __syncthreads();
  int cnt_gt = sh[0];
  int og = scan_a[tid], oe = cnt_gt + scan_b[tid];
  for (int i = start; i < end; i++) {
    int n = list[i];
    unsigned k = __float_as_uint(g_max_vals[n]);
    if (k > kth) {
      out_idx[og] = n; out_valid[og] = 1;
      if (out_val) out_val[og] = g_max_vals[n];
      og++;
    } else if (k == kth) {
      if (oe < K) {
        out_idx[oe] = n; out_valid[oe] = 1;
        if (out_val) out_val[oe] = g_max_vals[n];
      }
      oe++;
    }
  }
  __syncthreads();
}

// ---------------- decode helper ----------------
__device__ void decode_box(int n, const InPtrs& P, float* bb, float* cor,
                           float& area, float& scale, int& cls_out,
                           float* opx, float* opy) {
  int lvl, idx, hw; float px, py;
  point_info(n, lvl, idx, hw, px, py);
  const float* box = P.p[lvl * 4 + 1];
  const float* ang = P.p[lvl * 4 + 2];
  float l = box[idx], t = box[hw + idx], r = box[2 * hw + idx], b = box[3 * hw + idx];
  float a = ang[idx];
  float ca = cosf(a), sa = sinf(a);
  float w = l + r, h = t + b;
  float oxl = (r - l) * 0.5f, oyl = (b - t) * 0.5f;
  float ox = ca * oxl - sa * oyl;
  float oy = sa * oxl + ca * oyl;
  float an = mod_pos(a + HPI_F, PI_F) - HPI_F;
  float cx = px + ox, cy = py + oy;
  bb[0] = cx; bb[1] = cy; bb[2] = w; bb[3] = h; bb[4] = an;
  float c2 = cosf(an), s2 = sinf(an);
  const float dxs[4] = {-0.5f, 0.5f, 0.5f, -0.5f};
  const float dys[4] = {-0.5f, -0.5f, 0.5f, 0.5f};
#pragma unroll
  for (int k = 0; k < 4; k++) {
    float dx = dxs[k] * w, dy = dys[k] * h;
    cor[2 * k]     = cx + dx * c2 - dy * s2;
    cor[2 * k + 1] = cy + dx * s2 + dy * c2;
  }
  area = fabsf(w * h);
  scale = (float)lvl;
  cls_out = g_class_ind[n];
  if (opx) { *opx = px; *opy = py; }
}

__device__ void decode_to_pos_slot(int o, int n, const InPtrs& P) {
  float bb[5], cor[8], ar, sc; int cl;
  decode_box(n, P, bb, cor, ar, sc, cl, (float*)0, (float*)0);
#pragma unroll
  for (int k = 0; k < 5; k++) g_pos_bbox[o * 5 + k] = bb[k];
#pragma unroll
  for (int k = 0; k < 8; k++) g_pos_cor[o * 8 + k] = cor[k];
  g_pos_area[o] = ar; g_pos_scale[o] = sc; g_pos_class[o] = cl;
  g_pv[o] = g_max_vals[n];
}
__device__ void decode_to_hn_slot(int o, int n, const InPtrs& P) {
  float bb[5], cor[8], ar, sc, px, py; int cl;
  decode_box(n, P, bb, cor, ar, sc, cl, &px, &py);
#pragma unroll
  for (int k = 0; k < 8; k++) g_hn_cor[o * 8 + k] = cor[k];
  g_hn_area[o] = ar; g_hn_scale[o] = sc; g_hn_class[o] = cl;
  g_hn_px[o] = px; g_hn_py[o] = py;
}

// ---------------- convex quad intersection — fully register-resident ----------------
#define BPASS(KK, JJ)                                                      \
  _Pragma("unroll")                                                        \
  for (int i = 0; i < 32; i++) {                                           \
    int l = i ^ (JJ);                                                      \
    if (l > i) {                                                           \
      bool up = ((i & (KK)) == 0);                                         \
      float aa = sa_[i], ab = sa_[l];                                      \
      bool sw = up ? (aa > ab) : (aa < ab);                                \
      sa_[i] = sw ? ab : aa; sa_[l] = sw ? aa : ab;                        \
      float xi = sx_[i], xl = sx_[l];                                      \
      sx_[i] = sw ? xl : xi; sx_[l] = sw ? xi : xl;                        \
      float yi = sy_[i], yl = sy_[l];                                      \
      sy_[i] = sw ? yl : yi; sy_[l] = sw ? yi : yl;                        \
    }                                                                      \
  }

__device__ float inter_area(const float* __restrict__ A, const float* __restrict__ B) {
  float ax[4], ay[4], bx[4], by[4];
#pragma unroll
  for (int i = 0; i < 4; i++) {
    ax[i] = A[2 * i]; ay[i] = A[2 * i + 1];
    bx[i] = B[2 * i]; by[i] = B[2 * i + 1];
  }
  float dax[4], day[4], dbx[4], dby[4];
#pragma unroll
  for (int i = 0; i < 4; i++) {
    int i1 = (i + 1) & 3;
    dax[i] = ax[i1] - ax[i]; day[i] = ay[i1] - ay[i];
    dbx[i] = bx[i1] - bx[i]; dby[i] = by[i1] - by[i];
  }
  float px[24], py[24]; bool val[24];
#pragma unroll
  for (int i = 0; i < 4; i++) {
#pragma unroll
    for (int j = 0; j < 4; j++) {
      float dx = bx[j] - ax[i], dy = by[j] - ay[i];
      float den = crs(dax[i], day[i], dbx[j], dby[j]);
      float ad = fabsf(den);
      float ds = (ad < 1e-10f) ? 1.0f : den;
      float t = crs(dx, dy, dbx[j], dby[j]) / ds;
      float u = crs(dx, dy, dax[i], day[i]) / ds;
      bool ok = (ad > 1e-10f) & (t >= 0.f) & (t <= 1.f) & (u >= 0.f) & (u <= 1.f);
      int k = i * 4 + j;
      px[k] = ax[i] + t * dax[i];
      py[k] = ay[i] + t * day[i];
      val[k] = ok;
    }
  }
#pragma unroll
  for (int i = 0; i < 4; i++) {   // corners of A inside B
    bool ge = true, le = true;
#pragma unroll
    for (int j = 0; j < 4; j++) {
      float s = crs(dbx[j], dby[j], ax[i] - bx[j], ay[i] - by[j]);
      ge = ge && (s >= -1e-9f);
      le = le && (s <= 1e-9f);
    }
    val[16 + i] = ge || le; px[16 + i] = ax[i]; py[16 + i] = ay[i];
  }
#pragma unroll
  for (int j = 0; j < 4; j++) {   // corners of B inside A
    bool ge = true, le = true;
#pragma unroll
    for (int i = 0; i < 4; i++) {
      float s = crs(dax[i], day[i], bx[j] - ax[i], by[j] - ay[i]);
      ge = ge && (s >= -1e-9f);
      le = le && (s <= 1e-9f);
    }
    val[20 + j] = ge || le; px[20 + j] = bx[j]; py[20 + j] = by[j];
  }
  int n = 0; float sx = 0.f, sy = 0.f;
#pragma unroll
  for (int k = 0; k < 24; k++) if (val[k]) { n++; sx += px[k]; sy += py[k]; }
  float dn = (float)(n > 1 ? n : 1);
  float cx = sx / dn, cy = sy / dn;

  // 24 real slots (invalid collapse to centroid) + 8 +INF dummies; non-stable
  // network OK: angle ties only among identical centroid points (zero terms).
  float sa_[32], sx_[32], sy_[32];
#pragma unroll
  for (int k = 0; k < 24; k++) {
    float X = val[k] ? px[k] : cx;
    float Y = val[k] ? py[k] : cy;
    sx_[k] = X; sy_[k] = Y;
    sa_[k] = pseudo_ang(X - cx, Y - cy);
  }
#pragma unroll
  for (int k = 24; k < 32; k++) {
    sa_[k] = __int_as_float(0x7f800000);  // +inf
    sx_[k] = cx; sy_[k] = cy;
  }
  BPASS(2, 1)
  BPASS(4, 2)  BPASS(4, 1)
  BPASS(8, 4)  BPASS(8, 2)  BPASS(8, 1)
  BPASS(16, 8) BPASS(16, 4) BPASS(16, 2) BPASS(16, 1)
  BPASS(32, 16) BPASS(32, 8) BPASS(32, 4) BPASS(32, 2) BPASS(32, 1)

  float s2 = 0.f;
#pragma unroll
  for (int k = 0; k < 24; k++) {
    int k1 = (k + 1) % 24;
    s2 += crs(sx_[k] - cx, sy_[k] - cy, sx_[k1] - cx, sy_[k1] - cy);
  }
  float area = 0.5f * fabsf(s2);
  return (n >= 3) ? area : 0.f;
}

// ================= kernel 1: per-point stats + per-tile partials =================
__global__ __launch_bounds__(256) void k_prep(InPtrs P) {
  int tid = threadIdx.x;
  int t = blockIdx.x;
  int n = t * 256 + tid;
  __shared__ float r0[256], r1[256], r2[256];

  int lvl, idx, hw; float px, py;
  point_info(n, lvl, idx, hw, px, py);
  const float* cls = P.p[lvl * 4 + 0];
  const float* ctr = P.p[lvl * 4 + 3];
  float stiou = sigmoidf(ctr[idx]);
  float mv = -1.f, scm = 0.f; int ci = 0;
  for (int c = 0; c < NCLS; c++) {
    float sc = sigmoidf(cls[c * hw + idx]);
    if (sc > scm) scm = sc;
    float j = sc * stiou;
    if (j > mv) { mv = j; ci = c; }
  }
  g_max_vals[n] = mv;
  g_class_ind[n] = ci;
  g_sig_tiou[n] = stiou;
  g_sig_cls_max[n] = scm;
  g_hnflag[n] = 0;
  float isc = (mv >= 0.1f) ? 1.f : 0.f;
  r0[tid] = isc; r1[tid] = isc * mv; r2[tid] = isc * mv * mv;
  __syncthreads();
  for (int st = 128; st > 0; st >>= 1) {
    if (tid < st) { r0[tid] += r0[tid + st]; r1[tid] += r1[tid + st]; r2[tid] += r2[tid + st]; }
    __syncthreads();
  }
  if (tid == 0) {
    g_bcnt[t] = (int)r0[0];
    g_bsum[t] = r1[0];
    g_bsumsq[t] = r2[0];
  }
}

// ========== kernel 2: redundant threshold + masks + per-tile counts ==========
__global__ __launch_bounds__(256) void k_mask() {
  int tid = threadIdx.x;
  int t = blockIdx.x;
  int n = t * 256 + tid;
  __shared__ float s1[256], s2[256];
  __shared__ int s0[256];
  int c = 0; float s = 0.f, q = 0.f;
  for (int i = tid; i < TILES; i += 256) { c += g_bcnt[i]; s += g_bsum[i]; q += g_bsumsq[i]; }
  s0[tid] = c; s1[tid] = s; s2[tid] = q; __syncthreads();
  for (int st = 128; st > 0; st >>= 1) {
    if (tid < st) { s0[tid] += s0[tid + st]; s1[tid] += s1[tid + st]; s2[tid] += s2[tid + st]; }
    __syncthreads();
  }
  int nc = s0[0]; float sum = s1[0], sumsq = s2[0];
  float mean = sum / (float)(nc > 1 ? nc : 1);
  float E = sumsq - 2.f * mean * sum + (float)nc * mean * mean;
  if (E < 0.f) E = 0.f;
  float var = E / (float)((nc - 1) > 1 ? (nc - 1) : 1);
  float th = fminf(mean + sqrtf(var), 0.4f);
  if (nc == 0) th = __int_as_float(0x7f800000);  // +inf
  if (t == 0 && tid == 0) g_thresh = th;

  float v = g_max_vals[n];
  int pm = (v >= th) ? 1 : 0;
  int hm = (v >= 0.1f && v < th) ? 1 : 0;
  g_pos_mask[n] = pm; g_hn_mask[n] = hm;
  __syncthreads();
  __shared__ int t0[256], t1[256];
  t0[tid] = pm; t1[tid] = hm; __syncthreads();
  for (int st = 128; st > 0; st >>= 1) {
    if (tid < st) { t0[tid] += t0[tid + st]; t1[tid] += t1[tid + st]; }
    __syncthreads();
  }
  if (tid == 0) { g_bpos[t] = t0[0]; g_bhn[t] = t1[0]; }
}

// ========== kernel 3: offsets (per-block recompute) + compact + inline decode; tile 340 publishes totals ==========
__global__ __launch_bounds__(256) void k_compact(InPtrs P) {
  int tid = threadIdx.x;
  int t = blockIdx.x;
  int n = t * 256 + tid;
  __shared__ int si0[256], si1[256];

  // this block's exclusive offset (sum of counts of tiles < t)
  int cp = 0, ch = 0;
  for (int i = tid; i < t; i += 256) { cp += g_bpos[i]; ch += g_bhn[i]; }
  si0[tid] = cp; si1[tid] = ch; __syncthreads();
  for (int st = 128; st > 0; st >>= 1) {
    if (tid < st) { si0[tid] += si0[tid + st]; si1[tid] += si1[tid + st]; }
    __syncthreads();
  }
  int poff = si0[0], hoff = si1[0];
  __syncthreads();

  // in-tile inclusive scan of masks
  int pm = g_pos_mask[n], hm = g_hn_mask[n];
  si0[tid] = pm; si1[tid] = hm; __syncthreads();
  for (int off = 1; off < 256; off <<= 1) {
    int ap = (tid >= off) ? si0[tid - off] : 0;
    int ah = (tid >= off) ? si1[tid - off] : 0;
    __syncthreads();
    si0[tid] += ap; si1[tid] += ah;
    __syncthreads();
  }
  if (pm) {
    int o = poff + si0[tid] - pm;
    if (o < CAP) g_pos_cand[o] = n;
    if (o < KPOS) decode_to_pos_slot(o, n, P);
  }
  if (hm) {
    int o = hoff + si1[tid] - hm;
    if (o < CAP) g_hn_cand[o] = n;
    if (o < KHN) decode_to_hn_slot(o, n, P);
  }
  // tile 340 publishes totals + slow flag (plain stores; kernel boundary = fence)
  if (t == TILES - 1 && tid == 255) {
    int tp = poff + si0[255];
    int thn = hoff + si1[255];
    g_tp = tp; g_thn = thn;
    g_slow = (tp == 0 || tp > KPOS || thn > KHN) ? 1 : 0;
  }
}

// ========== kernel 4: slow-path selection + decode (no-op on fast path) ==========
__global__ __launch_bounds__(256) void k_select(InPtrs P) {
  if (!g_slow) return;
  __shared__ int hist[256], si0[256], si1[256], sh_i[2];
  int tid = threadIdx.x;
  int tp = g_tp, thn = g_thn;
  int fallback = (tp == 0) ? 1 : 0;
  // select (writes g_pidx/g_pvalid/g_pv, g_hidx/g_hvalid)
  if (!fallback && tp <= KPOS) {
    for (int i = tid; i < KPOS; i += 256) {
      if (i < tp) {
        int m = g_pos_cand[i];
        g_pidx[i] = m; g_pvalid[i] = 1; g_pv[i] = g_max_vals[m];
      } else { g_pidx[i] = 0; g_pvalid[i] = 0; g_pv[i] = -1.f; }
    }
    __syncthreads();
  } else if (!fallback && tp <= CAP) {
    radix_select_list(g_pos_cand, tp, KPOS, g_pidx, g_pvalid, g_pv, hist, si0, si1, sh_i);
  } else if (!fallback) {
    radix_select_mask(MASK_POS, KPOS, g_pidx, g_pvalid, g_pv, hist, si0, si1, sh_i);
  } else {
    radix_select_mask(MASK_ALL, 10, g_pidx, g_pvalid, g_pv, hist, si0, si1, sh_i);
    for (int i = tid; i < 10; i += 256)
      if (g_pvalid[i]) g_pos_mask[g_pidx[i]] = 1;
    for (int i = 10 + tid; i < KPOS; i += 256) {
      g_pidx[i] = 0; g_pvalid[i] = 0; g_pv[i] = -1.f;
    }
    __syncthreads();
  }
  if (thn <= KHN) {
    for (int i = tid; i < KHN; i += 256) {
      if (i < thn) { g_hidx[i] = g_hn_cand[i]; g_hvalid[i] = 1; }
      else { g_hidx[i] = 0; g_hvalid[i] = 0; }
    }
  } else if (thn <= CAP) {
    radix_select_list(g_hn_cand, thn, KHN, g_hidx, g_hvalid, (float*)0, hist, si0, si1, sh_i);
  } else {
    radix_select_mask(MASK_HN, KHN, g_hidx, g_hvalid, (float*)0, hist, si0, si1, sh_i);
  }
  __syncthreads();
  // decode selected into coalesced arrays (overwrites fast-path partial fills)
  for (int i = tid; i < KPOS; i += 256)
    if (g_pvalid[i]) { decode_to_pos_slot(i, g_pidx[i], P); }
  for (int i = tid; i < KHN; i += 256)
    if (g_hvalid[i]) { decode_to_hn_slot(i, g_hidx[i], P); }
}

// ============ kernel 5: IoU + aggregation + scatter (dense inter_area via compaction) ============
__global__ __launch_bounds__(256) void k_iou() {
  const int h = blockIdx.x;
  const int j = threadIdx.x;
  const int slow = g_slow;
  const int tp = g_tp, thn = g_thn;

  const int hv = slow ? g_hvalid[h] : ((h < thn) ? 1 : 0);
  if (!hv) return;   // block-uniform
  const int nh = slow ? g_hidx[h] : g_hn_cand[h];

  float hcor[8];
#pragma unroll
  for (int k = 0; k < 8; k++) hcor[k] = g_hn_cor[h * 8 + k];
  const float har = g_hn_area[h], hsc = g_hn_scale[h];
  const float hpx = g_hn_px[h], hpy = g_hn_py[h];
  const int hcl = g_hn_class[h];

  // phase 1: cheap prefilter per positive slot j
  const int pvld = slow ? g_pvalid[j] : ((j < tp) ? 1 : 0);
  bool pre = false;
  if (pvld) {
    pre = (g_pos_class[j] == hcl) && (fabsf(g_pos_scale[j] - hsc) <= 1.0f);
    if (pre) {
      float cx = g_pos_bbox[j * 5 + 0], cy = g_pos_bbox[j * 5 + 1];
      float bw = g_pos_bbox[j * 5 + 2], bh = g_pos_bbox[j * 5 + 3];
      float an = g_pos_bbox[j * 5 + 4];
      float ca = cosf(an), sa = sinf(an);
      float dx = hpx - cx, dy = hpy - cy;
      float ox = ca * dx + sa * dy, oy = -sa * dx + ca * dy;
      float mm = fminf(fminf(bw * 0.5f + ox, bw * 0.5f - ox),
                       fminf(bh * 0.5f + oy, bh * 0.5f - oy));
      pre = (mm > 0.f);
    }
  }

  // phase 2: index-compact surviving j's, run inter_area densely
  __shared__ int lst[256], scn[256];
  __shared__ float rw[7][256];
  scn[j] = pre ? 1 : 0;
#pragma unroll
  for (int k = 0; k < 7; k++) rw[k][j] = 0.f;
  __syncthreads();
  // inclusive scan of scn
  for (int off = 1; off < 256; off <<= 1) {
    int a = (j >= off) ? scn[j - off] : 0;
    __syncthreads();
    scn[j] += a;
    __syncthreads();
  }
  if (pre) lst[scn[j] - 1] = j;
  int nv = scn[255];
  __syncthreads();

  for (int i = j; i < nv; i += 256) {
    int jj = lst[i];
    float pcor[8];
#pragma unroll
    for (int k = 0; k < 8; k++) pcor[k] = g_pos_cor[jj * 8 + k];
    float inter = inter_area(hcor, pcor);
    float iou = inter / (har + g_pos_area[jj] - inter + 1e-8f);
    if (iou >= 0.6f) {
      float pv = g_pv[jj];
      rw[0][jj] = pv;
#pragma unroll
      for (int k = 0; k < 5; k++) rw[1 + k][jj] = pv * g_pos_bbox[jj * 5 + k];
      rw[6][jj] = 1.f;
    }
  }
  __syncthreads();
  // j-ordered tree reduction (same order as prior passing rounds)
  for (int st = 128; st > 0; st >>= 1) {
    if (j < st)
#pragma unroll
      for (int k = 0; k < 7; k++) rw[k][j] += rw[k][j + st];
    __syncthreads();
  }
  if (j == 0 && rw[6][0] > 0.f) {
    float inv = 1.f / fmaxf(rw[0][0], 1e-8f);
    float bb[5];
#pragma unroll
    for (int k = 0; k < 5; k++) bb[k] = rw[1 + k][0] * inv;
    float ca = cosf(bb[4]), sa = sinf(bb[4]);
    float dx = hpx - bb[0], dy = hpy - bb[1];
    float ox = ca * dx + sa * dy, oy = -sa * dx + ca * dy;
    g_loc_targets[nh * 5 + 0] = bb[2] * 0.5f + ox;
    g_loc_targets[nh * 5 + 1] = bb[3] * 0.5f + oy;
    g_loc_targets[nh * 5 + 2] = bb[2] * 0.5f - ox;
    g_loc_targets[nh * 5 + 3] = bb[3] * 0.5f - oy;
    g_loc_targets[nh * 5 + 4] = bb[4];
    g_hnflag[nh] = 1;
  }
}

// ============ kernel 6: per-point losses -> per-tile partials ============
__global__ __launch_bounds__(256) void k_loss(InPtrs P) {
  int tid = threadIdx.x;
  int t = blockIdx.x;
  int n = t * 256 + tid;
  __shared__ float red[6][256];
  float v0, v1, v2, v3, v4, v5;
  {
    int lvl, idx, hw; float px, py;
    point_info(n, lvl, idx, hw, px, py);
    int pm = g_pos_mask[n], hm = g_hn_mask[n], hf = g_hnflag[n];
    int sel = pm | hm;
    bool lp = (pm | hf) != 0;
    float ctmax = sel ? g_sig_cls_max[n] : 0.f;
    const float* tcls = P.p[lvl * 4 + 0];
    const float* tbox = P.p[lvl * 4 + 1];
    const float* tang = P.p[lvl * 4 + 2];
    const float* scls = P.p[20 + lvl * 4 + 0];
    const float* sbox = P.p[20 + lvl * 4 + 1];
    const float* sang = P.p[20 + lvl * 4 + 2];
    const float* sctr = P.p[20 + lvl * 4 + 3];
    float siou = sigmoidf(sctr[idx]);
    float scl = 0.f;
    for (int c = 0; c < NCLS; c++) {
      float jc = sigmoidf(scls[c * hw + idx]) * siou;
      float ct = sel ? sigmoidf(tcls[c * hw + idx]) : 0.f;
      float p = jc;
      if (p < 1e-12f) p = 1e-12f;
      float pu = 1.f - 1e-12f;
      if (p > pu) p = pu;
      float bce = -(ct * logf(p) + (1.f - ct) * log1pf(-p));
      float d = fabsf(jc - ct);
      scl += bce * d * d;
    }
    v0 = scl;
    float lw = lp ? ctmax : 0.f;
    float tgt[5];
    if (hf) {
#pragma unroll
      for (int k = 0; k < 5; k++) tgt[k] = g_loc_targets[n * 5 + k];
    } else if (pm) {
      tgt[0] = tbox[idx]; tgt[1] = tbox[hw + idx];
      tgt[2] = tbox[2 * hw + idx]; tgt[3] = tbox[3 * hw + idx];
      tgt[4] = tang[idx];
    } else {
#pragma unroll
      for (int k = 0; k < 5; k++) tgt[k] = 0.f;
    }
    float sb = 0.f;
#pragma unroll
    for (int k = 0; k < 5; k++) {
      float sv = (k < 4) ? sbox[k * hw + idx] : sang[idx];
      float d = fabsf(sv - tgt[k]);
      sb += (d < 1.f) ? 0.5f * d * d : d - 0.5f;
    }
    v1 = sb * lw;
    v2 = 0.f;
    if (lp) {
      float p = siou;
      if (p < 1e-12f) p = 1e-12f;
      float pu = 1.f - 1e-12f;
      if (p > pu) p = pu;
      float ti = g_sig_tiou[n];
      v2 = -(ti * logf(p) + (1.f - ti) * log1pf(-p));
    }
    v3 = pm ? ctmax : 0.f;   // cls_avg
    v4 = lw;                 // loc_avg
    v5 = lp ? 1.f : 0.f;     // iou_avg
  }
  red[0][tid] = v0; red[1][tid] = v1; red[2][tid] = v2;
  red[3][tid] = v3; red[4][tid] = v4; red[5][tid] = v5;
  __syncthreads();
  for (int st = 128; st > 0; st >>= 1) {
    if (tid < st)
#pragma unroll
      for (int k = 0; k < 6; k++) red[k][tid] += red[k][tid + st];
    __syncthreads();
  }
  if (tid == 0)
#pragma unroll
    for (int k = 0; k < 6; k++) g_partials[t * 6 + k] = red[k][0];
}

// ============ kernel 7: final reduce + output ============
__global__ __launch_bounds__(256) void k_final(float* out) {
  int tid = threadIdx.x;
  float a[6] = {0,0,0,0,0,0};
  for (int b = tid; b < TILES; b += 256)
#pragma unroll
    for (int k = 0; k < 6; k++) a[k] += g_partials[b * 6 + k];
  __shared__ float red[6][256];
#pragma unroll
  for (int k = 0; k < 6; k++) red[k][tid] = a[k];
  __syncthreads();
  for (int st = 128; st > 0; st >>= 1) {
    if (tid < st)
#pragma unroll
      for (int k = 0; k < 6; k++) red[k][tid] += red[k][tid + st];
    __syncthreads();
  }
  if (tid == 0) {
    out[0] = red[0][0] / fmaxf(red[3][0], 1e-8f);
    out[1] = red[1][0] / fmaxf(red[4][0], 1e-8f);
    out[2] = red[2][0] / fmaxf(red[5][0], 1.f);
  }
}

extern "C" void kernel_launch(void* const* d_in, const int* in_sizes, int n_in,
                              void* d_out, int out_size, void* d_ws, size_t ws_size,
                              hipStream_t stream) {
  (void)in_sizes; (void)n_in; (void)out_size; (void)d_ws; (void)ws_size;
  InPtrs P;
  for (int i = 0; i < 40; i++) P.p[i] = (const float*)d_in[i];
  k_prep<<<TILES, 256, 0, stream>>>(P);
  k_mask<<<TILES, 256, 0, stream>>>();
  k_compact<<<TILES, 256, 0, stream>>>(P);
  k_select<<<1, 256, 0, stream>>>(P);
  k_iou<<<KHN, 256, 0, stream>>>();
  k_loss<<<TILES, 256, 0, stream>>>(P);
  k_final<<<1, 256, 0, stream>>>((float*)d_out);
}